// Round 1
// baseline (1052.926 us; speedup 1.0000x reference)
//
#include <hip/hip_runtime.h>
#include <hip/hip_bf16.h>
#include <cstdint>
#include <cstddef>

// ---------- types ----------
typedef __attribute__((ext_vector_type(4))) float f32x4;
typedef __attribute__((ext_vector_type(8))) short s16x8;

__device__ __forceinline__ unsigned short f2bf(float f) {
    union { float f; unsigned u; } v; v.f = f;
    unsigned u = v.u;
    u += 0x7fffu + ((u >> 16) & 1u);      // round-to-nearest-even
    return (unsigned short)(u >> 16);
}

__device__ __forceinline__ void glds16(const void* g, void* l) {
    __builtin_amdgcn_global_load_lds(
        (const __attribute__((address_space(1))) unsigned int*)g,
        (__attribute__((address_space(3))) unsigned int*)l, 16, 0, 0);
}

// ---------- 1. ROI max pooling -> pooled bf16 [1024][25088] ----------
// pooled[n][c*49 + i*7 + j]
__global__ __launch_bounds__(256) void pool_kernel(
        const float* __restrict__ fm, const int* __restrict__ roi,
        unsigned short* __restrict__ pooled) {
    const int n = blockIdx.x;
    __shared__ int hs[7], he[7], wss[7], wee[7];
    if (threadIdx.x == 0) {
        int x0 = roi[n*4+0] / 16, y0 = roi[n*4+1] / 16;
        int x1 = roi[n*4+2] / 16, y1 = roi[n*4+3] / 16;
        if (x1 - x0 <= 1) { if (x1 < 84) x1 += 1; else x0 -= 1; }
        if (y1 - y0 <= 1) { if (y1 < 50) y1 += 1; else y0 -= 1; }
        int xs = min(max(x0, 0), 84), xe = min(max(x1, 0), 84);
        int ys = min(max(y0, 0), 50), ye = min(max(y1, 0), 50);
        int Lx = xe - xs, Ly = ye - ys;
        #pragma unroll
        for (int i = 0; i < 7; ++i) {
            int b0 = ys + (i * Ly) / 7, b1 = ys + ((i + 1) * Ly + 6) / 7;
            hs[i] = b0; he[i] = min(b1, b0 + 5);          // KMAX=5 window cap
            int c0 = xs + (i * Lx) / 7, c1 = xs + ((i + 1) * Lx + 6) / 7;
            wss[i] = c0; wee[i] = min(c1, c0 + 5);
        }
    }
    __syncthreads();
    unsigned short* orow = pooled + (size_t)n * 25088;
    for (int idx = threadIdx.x; idx < 25088; idx += 256) {
        int c = idx / 49, b = idx - c * 49, bi = b / 7, bj = b - bi * 7;
        const float* plane = fm + c * 4200;               // 50*84
        float m = -1e30f;
        int h0 = hs[bi], h1v = he[bi], w0 = wss[bj], w1v = wee[bj];
        for (int hh = h0; hh < h1v; ++hh) {
            const float* prow = plane + hh * 84;
            for (int ww = w0; ww < w1v; ++ww)
                m = fmaxf(m, prow[ww]);
        }
        orow[idx] = f2bf(m);
    }
}

// ---------- 2. transpose + f32->bf16: src[R][C] f32 -> dst[C][R] bf16 ----------
__global__ __launch_bounds__(256) void transpose_bf16(
        const float* __restrict__ src, unsigned short* __restrict__ dst,
        int R, int C) {
    __shared__ float tile[32][33];
    int c0 = blockIdx.x * 32, r0 = blockIdx.y * 32;
    int tx = threadIdx.x, ty = threadIdx.y;
    #pragma unroll
    for (int yy = ty; yy < 32; yy += 8)
        tile[yy][tx] = src[(size_t)(r0 + yy) * C + c0 + tx];
    __syncthreads();
    #pragma unroll
    for (int yy = ty; yy < 32; yy += 8)
        dst[(size_t)(c0 + yy) * R + r0 + tx] = f2bf(tile[tx][yy]);
}

// ---------- 3. bf16 GEMM, A[M][K] x BT[N][K] -> partial f32 [S][M][N] ----------
// 128x128 tile, BK=32, 4 waves (2x2 of 64x64), mfma_f32_16x16x32_bf16
__global__ __launch_bounds__(256) void gemm_bt_splitk(
        const unsigned short* __restrict__ A,
        const unsigned short* __restrict__ BT,
        float* __restrict__ part,
        int M, int N, int K, int ksteps) {
    __shared__ unsigned short As[128 * 32];
    __shared__ unsigned short Bs[128 * 32];
    const int t = threadIdx.x;
    const int lane = t & 63, wave = t >> 6;
    const int wr = wave >> 1, wc = wave & 1;
    const int m0 = blockIdx.y * 128, n0 = blockIdx.x * 128;
    const size_t kbase = (size_t)blockIdx.z * ksteps * 32;

    f32x4 acc[4][4];
    #pragma unroll
    for (int i = 0; i < 4; ++i)
        #pragma unroll
        for (int j = 0; j < 4; ++j)
            acc[i][j] = {0.f, 0.f, 0.f, 0.f};

    const int srow = t >> 2;            // 0..63
    const int skoff = (t & 3) * 8;      // k element offset
    const unsigned short* Ag0 = A + (size_t)(m0 + srow) * K + kbase + skoff;
    const unsigned short* Ag1 = A + (size_t)(m0 + 64 + srow) * K + kbase + skoff;
    const unsigned short* Bg0 = BT + (size_t)(n0 + srow) * K + kbase + skoff;
    const unsigned short* Bg1 = BT + (size_t)(n0 + 64 + srow) * K + kbase + skoff;
    unsigned short* Al0 = &As[t * 8];
    unsigned short* Al1 = &As[2048 + t * 8];
    unsigned short* Bl0 = &Bs[t * 8];
    unsigned short* Bl1 = &Bs[2048 + t * 8];

    const int lr = lane & 15;
    const int lkb = (lane >> 4) * 8;

    for (int s = 0; s < ksteps; ++s) {
        const int ko = s * 32;
        glds16(Ag0 + ko, Al0);
        glds16(Ag1 + ko, Al1);
        glds16(Bg0 + ko, Bl0);
        glds16(Bg1 + ko, Bl1);
        __syncthreads();                 // drains vmcnt before barrier
        s16x8 af[4], bff[4];
        #pragma unroll
        for (int mi = 0; mi < 4; ++mi)
            af[mi] = *(const s16x8*)&As[(wr * 64 + mi * 16 + lr) * 32 + lkb];
        #pragma unroll
        for (int ni = 0; ni < 4; ++ni)
            bff[ni] = *(const s16x8*)&Bs[(wc * 64 + ni * 16 + lr) * 32 + lkb];
        #pragma unroll
        for (int mi = 0; mi < 4; ++mi)
            #pragma unroll
            for (int ni = 0; ni < 4; ++ni)
                acc[mi][ni] = __builtin_amdgcn_mfma_f32_16x16x32_bf16(
                    af[mi], bff[ni], acc[mi][ni], 0, 0, 0);
        __syncthreads();
    }

    float* P = part + (size_t)blockIdx.z * ((size_t)M * N);
    #pragma unroll
    for (int mi = 0; mi < 4; ++mi) {
        #pragma unroll
        for (int ni = 0; ni < 4; ++ni) {
            int row = m0 + wr * 64 + mi * 16 + (lane >> 4) * 4;
            int col = n0 + wc * 64 + ni * 16 + lr;
            #pragma unroll
            for (int r = 0; r < 4; ++r)
                P[(size_t)(row + r) * N + col] = acc[mi][ni][r];
        }
    }
}

// ---------- 4. split-K reduce + bias (+optional bf16 cast) ----------
template<int OUTBF>
__global__ __launch_bounds__(256) void reduce_bias(
        const float* __restrict__ part, const float* __restrict__ bias,
        void* __restrict__ out, int MN, int N, int S) {
    int idx = blockIdx.x * 256 + threadIdx.x;
    if (idx >= MN) return;
    float s = 0.f;
    for (int i = 0; i < S; ++i) s += part[(size_t)i * MN + idx];
    s += bias[idx & (N - 1)];            // N = 4096 (pow2)
    if (OUTBF) ((unsigned short*)out)[idx] = f2bf(s);
    else       ((float*)out)[idx] = s;
}

// ---------- 5. heads: cls (softmax over 3) + reg (12) ----------
__global__ __launch_bounds__(256) void heads_kernel(
        const float* __restrict__ h, const float* __restrict__ Wc,
        const float* __restrict__ bc, const float* __restrict__ Wr,
        const float* __restrict__ br, float* __restrict__ out) {
    const int m = blockIdx.x;
    const int t = threadIdx.x;
    __shared__ float red[4][15];
    __shared__ float fin[15];
    const float* hr = h + (size_t)m * 4096;
    float v[15];
    #pragma unroll
    for (int j = 0; j < 15; ++j) v[j] = 0.f;
    for (int k = t; k < 4096; k += 256) {
        float hv = hr[k];
        const float* wc = Wc + k * 3;
        v[0] += hv * wc[0]; v[1] += hv * wc[1]; v[2] += hv * wc[2];
        const float* wr = Wr + k * 12;
        #pragma unroll
        for (int j = 0; j < 12; ++j) v[3 + j] += hv * wr[j];
    }
    const int lane = t & 63, wv = t >> 6;
    #pragma unroll
    for (int j = 0; j < 15; ++j) {
        float x = v[j];
        #pragma unroll
        for (int off = 32; off >= 1; off >>= 1)
            x += __shfl_down(x, off, 64);
        if (lane == 0) red[wv][j] = x;
    }
    __syncthreads();
    if (t < 15) {
        float s = red[0][t] + red[1][t] + red[2][t] + red[3][t];
        s += (t < 3) ? bc[t] : br[t - 3];
        fin[t] = s;
    }
    __syncthreads();
    if (t == 0) {
        float l0 = fin[0], l1 = fin[1], l2 = fin[2];
        float mx = fmaxf(l0, fmaxf(l1, l2));
        float e0 = expf(l0 - mx), e1 = expf(l1 - mx), e2 = expf(l2 - mx);
        float inv = 1.f / (e0 + e1 + e2);
        out[m * 3 + 0] = e0 * inv;
        out[m * 3 + 1] = e1 * inv;
        out[m * 3 + 2] = e2 * inv;
    }
    if (t >= 3 && t < 15) out[3072 + m * 12 + (t - 3)] = fin[t];
}

// ---------- launch ----------
extern "C" void kernel_launch(void* const* d_in, const int* in_sizes, int n_in,
                              void* d_out, int out_size, void* d_ws, size_t ws_size,
                              hipStream_t stream) {
    const float* featmap = (const float*)d_in[0];
    const int*   roi     = (const int*)d_in[1];
    const float* W1      = (const float*)d_in[2];
    const float* b1      = (const float*)d_in[3];
    const float* W2      = (const float*)d_in[4];
    const float* b2      = (const float*)d_in[5];
    const float* Wc      = (const float*)d_in[6];
    const float* bc      = (const float*)d_in[7];
    const float* Wr      = (const float*)d_in[8];
    const float* br      = (const float*)d_in[9];
    float* out = (float*)d_out;

    // workspace layout (bytes)
    char* ws = (char*)d_ws;
    unsigned short* pooled = (unsigned short*)(ws);                  //  51,380,224  [1024][25088] bf16
    unsigned short* W1T    = (unsigned short*)(ws + 51380224);       // 205,520,896  [4096][25088] bf16
    float*          part   = (float*)        (ws + 256901120);       //  67,108,864  [4][1024][4096] f32
    unsigned short* h1     = (unsigned short*)(ws + 324009984);      //   8,388,608  [1024][4096] bf16
    float*          hbuf   = (float*)        (ws + 332398592);       //  16,777,216  [1024][4096] f32
    unsigned short* W2T    = (unsigned short*)(ws + 51380224);       // alias of W1T (used after gemm1)

    const int M = 1024, N = 4096, K1 = 25088, K2 = 4096;

    pool_kernel<<<1024, 256, 0, stream>>>(featmap, roi, pooled);
    transpose_bf16<<<dim3(4096 / 32, 25088 / 32), dim3(32, 8), 0, stream>>>(W1, W1T, K1, N);
    gemm_bt_splitk<<<dim3(N / 128, M / 128, 4), 256, 0, stream>>>(pooled, W1T, part, M, N, K1, 196);
    transpose_bf16<<<dim3(4096 / 32, 4096 / 32), dim3(32, 8), 0, stream>>>(W2, W2T, K2, N);
    reduce_bias<1><<<(M * N) / 256, 256, 0, stream>>>(part, b1, h1, M * N, N, 4);
    gemm_bt_splitk<<<dim3(N / 128, M / 128, 2), 256, 0, stream>>>(h1, W2T, part, M, N, K2, 64);
    reduce_bias<0><<<(M * N) / 256, 256, 0, stream>>>(part, b2, hbuf, M * N, N, 2);
    heads_kernel<<<1024, 256, 0, stream>>>(hbuf, Wc, bc, Wr, br, out);
}

// Round 2
// 759.217 us; speedup vs baseline: 1.3869x; 1.3869x over previous
//
#include <hip/hip_runtime.h>
#include <hip/hip_bf16.h>
#include <cstdint>
#include <cstddef>

// ---------- types ----------
typedef __attribute__((ext_vector_type(4))) float f32x4;
typedef __attribute__((ext_vector_type(8))) short s16x8;

__device__ __forceinline__ unsigned short f2bf(float f) {
    union { float f; unsigned u; } v; v.f = f;
    unsigned u = v.u;
    u += 0x7fffu + ((u >> 16) & 1u);      // round-to-nearest-even
    return (unsigned short)(u >> 16);
}
__device__ __forceinline__ float bf2f(unsigned short u) {
    union { unsigned u; float f; } v; v.u = ((unsigned)u) << 16; return v.f;
}

__device__ __forceinline__ void glds16(const void* g, void* l) {
    __builtin_amdgcn_global_load_lds(
        (const __attribute__((address_space(1))) unsigned int*)g,
        (__attribute__((address_space(3))) unsigned int*)l, 16, 0, 0);
}

// ---------- 0. featmap transpose: fm[512][4200] f32 -> fmT[4200][512] bf16 ----------
__global__ __launch_bounds__(256) void transpose_fm(
        const float* __restrict__ fm, unsigned short* __restrict__ fmT) {
    __shared__ float tile[32][33];
    int p0 = blockIdx.x * 32, c0 = blockIdx.y * 32;
    int tx = threadIdx.x, ty = threadIdx.y;      // (32,8)
    #pragma unroll
    for (int yy = ty; yy < 32; yy += 8) {
        int p = p0 + tx;
        if (p < 4200) tile[yy][tx] = fm[(size_t)(c0 + yy) * 4200 + p];
    }
    __syncthreads();
    #pragma unroll
    for (int yy = ty; yy < 32; yy += 8) {
        int p = p0 + yy;
        if (p < 4200) fmT[(size_t)p * 512 + c0 + tx] = f2bf(tile[tx][yy]);
    }
}

// ---------- 1. ROI max pooling (channel-last) -> pooled bf16 [1024][b*512+c] ----------
__global__ __launch_bounds__(256) void pool_kernel2(
        const unsigned short* __restrict__ fmT, const int* __restrict__ roi,
        unsigned short* __restrict__ pooled) {
    const int n = blockIdx.x;
    __shared__ int hs[7], he[7], wss[7], wee[7];
    if (threadIdx.x == 0) {
        int x0 = roi[n*4+0] / 16, y0 = roi[n*4+1] / 16;
        int x1 = roi[n*4+2] / 16, y1 = roi[n*4+3] / 16;
        if (x1 - x0 <= 1) { if (x1 < 84) x1 += 1; else x0 -= 1; }
        if (y1 - y0 <= 1) { if (y1 < 50) y1 += 1; else y0 -= 1; }
        int xs = min(max(x0, 0), 84), xe = min(max(x1, 0), 84);
        int ys = min(max(y0, 0), 50), ye = min(max(y1, 0), 50);
        int Lx = xe - xs, Ly = ye - ys;
        #pragma unroll
        for (int i = 0; i < 7; ++i) {
            int b0 = ys + (i * Ly) / 7, b1 = ys + ((i + 1) * Ly + 6) / 7;
            hs[i] = b0; he[i] = min(b1, b0 + 5);          // KMAX=5 window cap
            int c0 = xs + (i * Lx) / 7, c1 = xs + ((i + 1) * Lx + 6) / 7;
            wss[i] = c0; wee[i] = min(c1, c0 + 5);
        }
    }
    __syncthreads();
    const int t = threadIdx.x;                    // channel pair = 2t, 2t+1
    unsigned short* orow = pooled + (size_t)n * 25088;
    for (int bi = 0; bi < 7; ++bi) {
        const int h0 = hs[bi], h1 = he[bi];
        for (int bj = 0; bj < 7; ++bj) {
            const int w0 = wss[bj], w1 = wee[bj];
            float m0 = -1e30f, m1 = -1e30f;
            for (int hh = h0; hh < h1; ++hh) {
                const unsigned short* base = fmT + (size_t)(hh * 84) * 512 + 2 * t;
                for (int ww = w0; ww < w1; ++ww) {
                    ushort2 v = *(const ushort2*)(base + ww * 512);
                    m0 = fmaxf(m0, bf2f(v.x));
                    m1 = fmaxf(m1, bf2f(v.y));
                }
            }
            ushort2 o; o.x = f2bf(m0); o.y = f2bf(m1);
            *(ushort2*)(orow + (bi * 7 + bj) * 512 + 2 * t) = o;
        }
    }
}

// ---------- 2a. W1 permuted transpose: W1[c*49+b][j] f32 -> W1T[j][b*512+c] bf16 ----------
__global__ __launch_bounds__(256) void transpose_w1_perm(
        const float* __restrict__ W1, unsigned short* __restrict__ W1T) {
    __shared__ float tile[64][65];
    const int b  = blockIdx.z;          // 0..48
    const int c0 = blockIdx.y * 64;     // channel block
    const int j0 = blockIdx.x * 64;     // output-col block
    const int tx = threadIdx.x;         // 0..63
    const int ty = threadIdx.y;         // 0..3
    #pragma unroll
    for (int cy = ty; cy < 64; cy += 4)
        tile[cy][tx] = W1[((size_t)(c0 + cy) * 49 + b) * 4096 + j0 + tx];
    __syncthreads();
    #pragma unroll
    for (int jy = ty; jy < 64; jy += 4)
        W1T[(size_t)(j0 + jy) * 25088 + b * 512 + c0 + tx] = f2bf(tile[tx][jy]);
}

// ---------- 2b. generic transpose + f32->bf16: src[R][C] f32 -> dst[C][R] bf16 ----------
__global__ __launch_bounds__(256) void transpose_bf16(
        const float* __restrict__ src, unsigned short* __restrict__ dst,
        int R, int C) {
    __shared__ float tile[32][33];
    int c0 = blockIdx.x * 32, r0 = blockIdx.y * 32;
    int tx = threadIdx.x, ty = threadIdx.y;
    #pragma unroll
    for (int yy = ty; yy < 32; yy += 8)
        tile[yy][tx] = src[(size_t)(r0 + yy) * C + c0 + tx];
    __syncthreads();
    #pragma unroll
    for (int yy = ty; yy < 32; yy += 8)
        dst[(size_t)(c0 + yy) * R + r0 + tx] = f2bf(tile[tx][yy]);
}

// ---------- 3. bf16 GEMM, A[M][K] x BT[N][K] -> partial f32 [S][M][N] ----------
__global__ __launch_bounds__(256) void gemm_bt_splitk(
        const unsigned short* __restrict__ A,
        const unsigned short* __restrict__ BT,
        float* __restrict__ part,
        int M, int N, int K, int ksteps) {
    __shared__ unsigned short As[128 * 32];
    __shared__ unsigned short Bs[128 * 32];
    const int t = threadIdx.x;
    const int lane = t & 63, wave = t >> 6;
    const int wr = wave >> 1, wc = wave & 1;
    const int m0 = blockIdx.y * 128, n0 = blockIdx.x * 128;
    const size_t kbase = (size_t)blockIdx.z * ksteps * 32;

    f32x4 acc[4][4];
    #pragma unroll
    for (int i = 0; i < 4; ++i)
        #pragma unroll
        for (int j = 0; j < 4; ++j)
            acc[i][j] = {0.f, 0.f, 0.f, 0.f};

    const int srow = t >> 2;
    const int skoff = (t & 3) * 8;
    const unsigned short* Ag0 = A + (size_t)(m0 + srow) * K + kbase + skoff;
    const unsigned short* Ag1 = A + (size_t)(m0 + 64 + srow) * K + kbase + skoff;
    const unsigned short* Bg0 = BT + (size_t)(n0 + srow) * K + kbase + skoff;
    const unsigned short* Bg1 = BT + (size_t)(n0 + 64 + srow) * K + kbase + skoff;
    unsigned short* Al0 = &As[t * 8];
    unsigned short* Al1 = &As[2048 + t * 8];
    unsigned short* Bl0 = &Bs[t * 8];
    unsigned short* Bl1 = &Bs[2048 + t * 8];

    const int lr = lane & 15;
    const int lkb = (lane >> 4) * 8;

    for (int s = 0; s < ksteps; ++s) {
        const int ko = s * 32;
        glds16(Ag0 + ko, Al0);
        glds16(Ag1 + ko, Al1);
        glds16(Bg0 + ko, Bl0);
        glds16(Bg1 + ko, Bl1);
        __syncthreads();
        s16x8 af[4], bff[4];
        #pragma unroll
        for (int mi = 0; mi < 4; ++mi)
            af[mi] = *(const s16x8*)&As[(wr * 64 + mi * 16 + lr) * 32 + lkb];
        #pragma unroll
        for (int ni = 0; ni < 4; ++ni)
            bff[ni] = *(const s16x8*)&Bs[(wc * 64 + ni * 16 + lr) * 32 + lkb];
        #pragma unroll
        for (int mi = 0; mi < 4; ++mi)
            #pragma unroll
            for (int ni = 0; ni < 4; ++ni)
                acc[mi][ni] = __builtin_amdgcn_mfma_f32_16x16x32_bf16(
                    af[mi], bff[ni], acc[mi][ni], 0, 0, 0);
        __syncthreads();
    }

    float* P = part + (size_t)blockIdx.z * ((size_t)M * N);
    #pragma unroll
    for (int mi = 0; mi < 4; ++mi) {
        #pragma unroll
        for (int ni = 0; ni < 4; ++ni) {
            int row = m0 + wr * 64 + mi * 16 + (lane >> 4) * 4;
            int col = n0 + wc * 64 + ni * 16 + lr;
            #pragma unroll
            for (int r = 0; r < 4; ++r)
                P[(size_t)(row + r) * N + col] = acc[mi][ni][r];
        }
    }
}

// ---------- 4. split-K reduce + bias (+optional bf16 cast) ----------
template<int OUTBF>
__global__ __launch_bounds__(256) void reduce_bias(
        const float* __restrict__ part, const float* __restrict__ bias,
        void* __restrict__ out, int MN, int N, int S) {
    int idx = blockIdx.x * 256 + threadIdx.x;
    if (idx >= MN) return;
    float s = 0.f;
    for (int i = 0; i < S; ++i) s += part[(size_t)i * MN + idx];
    s += bias[idx & (N - 1)];
    if (OUTBF) ((unsigned short*)out)[idx] = f2bf(s);
    else       ((float*)out)[idx] = s;
}

// ---------- 5. heads: cls (softmax over 3) + reg (12) ----------
__global__ __launch_bounds__(256) void heads_kernel(
        const float* __restrict__ h, const float* __restrict__ Wc,
        const float* __restrict__ bc, const float* __restrict__ Wr,
        const float* __restrict__ br, float* __restrict__ out) {
    const int m = blockIdx.x;
    const int t = threadIdx.x;
    __shared__ float red[4][15];
    __shared__ float fin[15];
    const float* hr = h + (size_t)m * 4096;
    float v[15];
    #pragma unroll
    for (int j = 0; j < 15; ++j) v[j] = 0.f;
    for (int k = t; k < 4096; k += 256) {
        float hv = hr[k];
        const float* wc = Wc + k * 3;
        v[0] += hv * wc[0]; v[1] += hv * wc[1]; v[2] += hv * wc[2];
        const float* wr = Wr + k * 12;
        #pragma unroll
        for (int j = 0; j < 12; ++j) v[3 + j] += hv * wr[j];
    }
    const int lane = t & 63, wv = t >> 6;
    #pragma unroll
    for (int j = 0; j < 15; ++j) {
        float x = v[j];
        #pragma unroll
        for (int off = 32; off >= 1; off >>= 1)
            x += __shfl_down(x, off, 64);
        if (lane == 0) red[wv][j] = x;
    }
    __syncthreads();
    if (t < 15) {
        float s = red[0][t] + red[1][t] + red[2][t] + red[3][t];
        s += (t < 3) ? bc[t] : br[t - 3];
        fin[t] = s;
    }
    __syncthreads();
    if (t == 0) {
        float l0 = fin[0], l1 = fin[1], l2 = fin[2];
        float mx = fmaxf(l0, fmaxf(l1, l2));
        float e0 = expf(l0 - mx), e1 = expf(l1 - mx), e2 = expf(l2 - mx);
        float inv = 1.f / (e0 + e1 + e2);
        out[m * 3 + 0] = e0 * inv;
        out[m * 3 + 1] = e1 * inv;
        out[m * 3 + 2] = e2 * inv;
    }
    if (t >= 3 && t < 15) out[3072 + m * 12 + (t - 3)] = fin[t];
}

// ---------- launch ----------
extern "C" void kernel_launch(void* const* d_in, const int* in_sizes, int n_in,
                              void* d_out, int out_size, void* d_ws, size_t ws_size,
                              hipStream_t stream) {
    const float* featmap = (const float*)d_in[0];
    const int*   roi     = (const int*)d_in[1];
    const float* W1      = (const float*)d_in[2];
    const float* b1      = (const float*)d_in[3];
    const float* W2      = (const float*)d_in[4];
    const float* b2      = (const float*)d_in[5];
    const float* Wc      = (const float*)d_in[6];
    const float* bc      = (const float*)d_in[7];
    const float* Wr      = (const float*)d_in[8];
    const float* br      = (const float*)d_in[9];
    float* out = (float*)d_out;

    // workspace layout (bytes)
    char* ws = (char*)d_ws;
    unsigned short* pooled = (unsigned short*)(ws);                  //  51,380,224  [1024][25088] bf16 (k' = b*512+c)
    unsigned short* W1T    = (unsigned short*)(ws + 51380224);       // 205,520,896  [4096][25088] bf16 (k' order)
    float*          part   = (float*)        (ws + 256901120);       //  67,108,864  [4][1024][4096] f32
    unsigned short* h1     = (unsigned short*)(ws + 324009984);      //   8,388,608  [1024][4096] bf16
    float*          hbuf   = (float*)        (ws + 332398592);       //  16,777,216  [1024][4096] f32
    unsigned short* W2T    = (unsigned short*)(ws + 51380224);       // alias of W1T (used after gemm1)
    unsigned short* fmT    = (unsigned short*)(ws + 256901120);      // alias of part (dead before gemm1): 4,300,800 [4200][512] bf16

    const int M = 1024, N = 4096, K1 = 25088, K2 = 4096;

    transpose_fm<<<dim3(132, 16), dim3(32, 8), 0, stream>>>(featmap, fmT);
    pool_kernel2<<<1024, 256, 0, stream>>>(fmT, roi, pooled);
    transpose_w1_perm<<<dim3(64, 8, 49), dim3(64, 4), 0, stream>>>(W1, W1T);
    gemm_bt_splitk<<<dim3(N / 128, M / 128, 4), 256, 0, stream>>>(pooled, W1T, part, M, N, K1, 196);
    transpose_bf16<<<dim3(4096 / 32, 4096 / 32), dim3(32, 8), 0, stream>>>(W2, W2T, K2, N);
    reduce_bias<1><<<(M * N) / 256, 256, 0, stream>>>(part, b1, h1, M * N, N, 4);
    gemm_bt_splitk<<<dim3(N / 128, M / 128, 2), 256, 0, stream>>>(h1, W2T, part, M, N, K2, 64);
    reduce_bias<0><<<(M * N) / 256, 256, 0, stream>>>(part, b2, hbuf, M * N, N, 2);
    heads_kernel<<<1024, 256, 0, stream>>>(hbuf, Wc, bc, Wr, br, out);
}

// Round 4
// 622.975 us; speedup vs baseline: 1.6902x; 1.2187x over previous
//
#include <hip/hip_runtime.h>
#include <hip/hip_bf16.h>
#include <cstdint>
#include <cstddef>

// ---------- types ----------
typedef __attribute__((ext_vector_type(4))) float f32x4;
typedef __attribute__((ext_vector_type(8))) short s16x8;

__device__ __forceinline__ unsigned short f2bf(float f) {
    union { float f; unsigned u; } v; v.f = f;
    unsigned u = v.u;
    u += 0x7fffu + ((u >> 16) & 1u);      // round-to-nearest-even
    return (unsigned short)(u >> 16);
}
__device__ __forceinline__ float bf2f(unsigned short u) {
    union { unsigned u; float f; } v; v.u = ((unsigned)u) << 16; return v.f;
}

__device__ __forceinline__ void glds16(const void* g, void* l) {
    __builtin_amdgcn_global_load_lds(
        (const __attribute__((address_space(1))) unsigned int*)g,
        (__attribute__((address_space(3))) unsigned int*)l, 16, 0, 0);
}

#define MEMFENCE asm volatile("" ::: "memory")

// ---------- 0. featmap transpose: fm[512][4200] f32 -> fmT[4200][512] bf16 ----------
__global__ __launch_bounds__(256) void transpose_fm(
        const float* __restrict__ fm, unsigned short* __restrict__ fmT) {
    __shared__ float tile[32][33];
    int p0 = blockIdx.x * 32, c0 = blockIdx.y * 32;
    int tx = threadIdx.x, ty = threadIdx.y;      // (32,8)
    #pragma unroll
    for (int yy = ty; yy < 32; yy += 8) {
        int p = p0 + tx;
        if (p < 4200) tile[yy][tx] = fm[(size_t)(c0 + yy) * 4200 + p];
    }
    __syncthreads();
    #pragma unroll
    for (int yy = ty; yy < 32; yy += 8) {
        int p = p0 + yy;
        if (p < 4200) fmT[(size_t)p * 512 + c0 + tx] = f2bf(tile[tx][yy]);
    }
}

// ---------- 1. ROI max pooling (channel-last) -> pooled bf16 [1024][b*512+c] ----------
__global__ __launch_bounds__(256) void pool_kernel2(
        const unsigned short* __restrict__ fmT, const int* __restrict__ roi,
        unsigned short* __restrict__ pooled) {
    const int n = blockIdx.x;
    __shared__ int hs[7], he[7], wss[7], wee[7];
    if (threadIdx.x == 0) {
        int x0 = roi[n*4+0] / 16, y0 = roi[n*4+1] / 16;
        int x1 = roi[n*4+2] / 16, y1 = roi[n*4+3] / 16;
        if (x1 - x0 <= 1) { if (x1 < 84) x1 += 1; else x0 -= 1; }
        if (y1 - y0 <= 1) { if (y1 < 50) y1 += 1; else y0 -= 1; }
        int xs = min(max(x0, 0), 84), xe = min(max(x1, 0), 84);
        int ys = min(max(y0, 0), 50), ye = min(max(y1, 0), 50);
        int Lx = xe - xs, Ly = ye - ys;
        #pragma unroll
        for (int i = 0; i < 7; ++i) {
            int b0 = ys + (i * Ly) / 7, b1 = ys + ((i + 1) * Ly + 6) / 7;
            hs[i] = b0; he[i] = min(b1, b0 + 5);
            int c0 = xs + (i * Lx) / 7, c1 = xs + ((i + 1) * Lx + 6) / 7;
            wss[i] = c0; wee[i] = min(c1, c0 + 5);
        }
    }
    __syncthreads();
    const int t = threadIdx.x;
    unsigned short* orow = pooled + (size_t)n * 25088;
    for (int bi = 0; bi < 7; ++bi) {
        const int h0 = hs[bi], h1 = he[bi];
        for (int bj = 0; bj < 7; ++bj) {
            const int w0 = wss[bj], w1 = wee[bj];
            float m0 = -1e30f, m1 = -1e30f;
            for (int hh = h0; hh < h1; ++hh) {
                const unsigned short* base = fmT + (size_t)(hh * 84) * 512 + 2 * t;
                for (int ww = w0; ww < w1; ++ww) {
                    ushort2 v = *(const ushort2*)(base + ww * 512);
                    m0 = fmaxf(m0, bf2f(v.x));
                    m1 = fmaxf(m1, bf2f(v.y));
                }
            }
            ushort2 o; o.x = f2bf(m0); o.y = f2bf(m1);
            *(ushort2*)(orow + (bi * 7 + bj) * 512 + 2 * t) = o;
        }
    }
}

// ---------- 2a. W1 permuted transpose: W1[c*49+b][j] f32 -> W1T[j][b*512+c] bf16 ----------
__global__ __launch_bounds__(256) void transpose_w1_perm(
        const float* __restrict__ W1, unsigned short* __restrict__ W1T) {
    __shared__ float tile[64][65];
    const int b  = blockIdx.z;          // 0..48
    const int c0 = blockIdx.y * 64;     // channel block
    const int j0 = blockIdx.x * 64;     // output-col block
    const int tx = threadIdx.x;         // 0..31
    const int ty = threadIdx.y;         // 0..7
    #pragma unroll
    for (int cy = ty; cy < 64; cy += 8) {
        const float* src = &W1[((size_t)(c0 + cy) * 49 + b) * 4096 + j0];
        tile[cy][tx]      = src[tx];
        tile[cy][tx + 32] = src[tx + 32];
    }
    __syncthreads();
    #pragma unroll
    for (int jy = ty; jy < 64; jy += 8) {
        ushort2 o;
        o.x = f2bf(tile[2 * tx][jy]);
        o.y = f2bf(tile[2 * tx + 1][jy]);
        *(ushort2*)&W1T[(size_t)(j0 + jy) * 25088 + b * 512 + c0 + 2 * tx] = o;
    }
}

// ---------- 2b. generic transpose + f32->bf16: src[R][C] f32 -> dst[C][R] bf16 ----------
__global__ __launch_bounds__(256) void transpose_bf16(
        const float* __restrict__ src, unsigned short* __restrict__ dst,
        int R, int C) {
    __shared__ float tile[32][33];
    int c0 = blockIdx.x * 32, r0 = blockIdx.y * 32;
    int tx = threadIdx.x, ty = threadIdx.y;
    #pragma unroll
    for (int yy = ty; yy < 32; yy += 8)
        tile[yy][tx] = src[(size_t)(r0 + yy) * C + c0 + tx];
    __syncthreads();
    #pragma unroll
    for (int yy = ty; yy < 32; yy += 8)
        dst[(size_t)(c0 + yy) * R + r0 + tx] = f2bf(tile[tx][yy]);
}

// ---------- 3. 256x256x64 8-phase bf16 GEMM (T2 swizzle + T3/T4 counted vmcnt + T5) ----
// Stage stream per iter tau: P0:A0(t+1) P1:A1(t+1) P2:B0(t+2) P3:B1(t+2).
// Steady state: exactly 6 loads issued after A1(tau) => vmcnt(6) at tau P0
// guarantees tile tau fully landed.  TAIL FIX (round-3 bug): in the final
// iteration those 6 stages are skipped (th>=kTiles), so vmcnt(6) passed
// without draining A(last) -> race.  Final iteration now uses vmcnt(0).
__global__ __launch_bounds__(512, 2) void gemm256(
        const unsigned short* __restrict__ A,
        const unsigned short* __restrict__ BT,
        float* __restrict__ part,
        int M, int N, int K, int kTiles) {
    extern __shared__ char smem[];
    const int t = threadIdx.x;
    const int lane = t & 63;
    const int wave = t >> 6;            // 0..7
    const int wr = wave >> 2;           // 0..1  (M half)
    const int wcn = wave & 3;           // 0..3  (N quarter)
    const int m0 = blockIdx.y * 256, n0 = blockIdx.x * 256;
    const long kbase = (long)blockIdx.z * kTiles * 64;

    const int lr = lane & 15;
    const int lks = lane >> 4;          // 0..3 (16B slot within 32-k slice)

    f32x4 acc[8][4];
    #pragma unroll
    for (int i = 0; i < 8; ++i)
        #pragma unroll
        for (int j = 0; j < 4; ++j)
            acc[i][j] = {0.f, 0.f, 0.f, 0.f};

    // ---- staging: half j of K-tile th (j: 0,1 = A halves; 2,3 = B halves) ----
    auto STAGE = [&](int th, int j) {
        if (th >= kTiles) return;
        char* lbase = smem + (th & 1) * 65536 +
                      (j < 2 ? j * 16384 : 32768 + (j - 2) * 16384);
        const unsigned short* gsrc = (j < 2)
            ? (A  + (long)(m0 + j * 128) * K + kbase + (long)th * 64)
            : (BT + (long)(n0 + (j - 2) * 128) * K + kbase + (long)th * 64);
        #pragma unroll
        for (int ci = 0; ci < 2; ++ci) {
            int s = ci * 512 + t;                // slot 0..1023
            int row = s >> 3, cs = s & 7;
            int csw = cs ^ (row & 7);            // inverse-swizzled source colslot
            glds16(gsrc + (long)row * K + csw * 8, lbase + s * 16);
        }
    };

    int curbuf = 0;
    auto LDA = [&](int mi, int ks) -> s16x8 {    // A frag: rows wr*128+mi*16+lr
        int rh = mi * 16 + lr;
        int slot = ks * 4 + lks;
        const char* p = smem + curbuf * 65536 + wr * 16384 +
                        rh * 128 + ((slot ^ (rh & 7)) * 16);
        return *(const s16x8*)p;
    };
    auto LDB = [&](int ni, int ks) -> s16x8 {    // B frag: n rows wcn*64+ni*16+lr
        int n = wcn * 64 + ni * 16 + lr;
        int rh = n & 127, half = n >> 7;
        int slot = ks * 4 + lks;
        const char* p = smem + curbuf * 65536 + 32768 + half * 16384 +
                        rh * 128 + ((slot ^ (rh & 7)) * 16);
        return *(const s16x8*)p;
    };

    // ---- prologue: B0(0) B1(0) A0(0) A1(0) B0(1) B1(1) = 12 loads ----
    STAGE(0, 2); STAGE(0, 3); STAGE(0, 0); STAGE(0, 1); STAGE(1, 2); STAGE(1, 3);

    s16x8 bfr[4][2];
    for (int tau = 0; tau < kTiles; ++tau) {
        curbuf = tau & 1;
        // ---------------- P0: B all (8 reads) + A frags 0,1 ----------------
        STAGE(tau + 1, 0);
        if (tau == kTiles - 1)
            asm volatile("s_waitcnt vmcnt(0)" ::: "memory");   // tail drain (bug fix)
        else
            asm volatile("s_waitcnt vmcnt(6)" ::: "memory");
        __builtin_amdgcn_s_barrier();
        MEMFENCE;
        #pragma unroll
        for (int ni = 0; ni < 4; ++ni) {
            bfr[ni][0] = LDB(ni, 0);
            bfr[ni][1] = LDB(ni, 1);
        }
        {
            s16x8 a00 = LDA(0, 0), a01 = LDA(0, 1), a10 = LDA(1, 0), a11 = LDA(1, 1);
            __builtin_amdgcn_s_setprio(1);
            #pragma unroll
            for (int ni = 0; ni < 4; ++ni) {
                acc[0][ni] = __builtin_amdgcn_mfma_f32_16x16x32_bf16(a00, bfr[ni][0], acc[0][ni], 0, 0, 0);
                acc[0][ni] = __builtin_amdgcn_mfma_f32_16x16x32_bf16(a01, bfr[ni][1], acc[0][ni], 0, 0, 0);
                acc[1][ni] = __builtin_amdgcn_mfma_f32_16x16x32_bf16(a10, bfr[ni][0], acc[1][ni], 0, 0, 0);
                acc[1][ni] = __builtin_amdgcn_mfma_f32_16x16x32_bf16(a11, bfr[ni][1], acc[1][ni], 0, 0, 0);
            }
            __builtin_amdgcn_s_setprio(0);
        }
        MEMFENCE;
        __builtin_amdgcn_s_barrier();
        MEMFENCE;
        // ---------------- P1: A frags 2,3 ----------------
        STAGE(tau + 1, 1);
        {
            s16x8 a00 = LDA(2, 0), a01 = LDA(2, 1), a10 = LDA(3, 0), a11 = LDA(3, 1);
            __builtin_amdgcn_s_setprio(1);
            #pragma unroll
            for (int ni = 0; ni < 4; ++ni) {
                acc[2][ni] = __builtin_amdgcn_mfma_f32_16x16x32_bf16(a00, bfr[ni][0], acc[2][ni], 0, 0, 0);
                acc[2][ni] = __builtin_amdgcn_mfma_f32_16x16x32_bf16(a01, bfr[ni][1], acc[2][ni], 0, 0, 0);
                acc[3][ni] = __builtin_amdgcn_mfma_f32_16x16x32_bf16(a10, bfr[ni][0], acc[3][ni], 0, 0, 0);
                acc[3][ni] = __builtin_amdgcn_mfma_f32_16x16x32_bf16(a11, bfr[ni][1], acc[3][ni], 0, 0, 0);
            }
            __builtin_amdgcn_s_setprio(0);
        }
        MEMFENCE;
        __builtin_amdgcn_s_barrier();
        MEMFENCE;
        // ---------------- P2: A frags 4,5 ----------------
        STAGE(tau + 2, 2);
        {
            s16x8 a00 = LDA(4, 0), a01 = LDA(4, 1), a10 = LDA(5, 0), a11 = LDA(5, 1);
            __builtin_amdgcn_s_setprio(1);
            #pragma unroll
            for (int ni = 0; ni < 4; ++ni) {
                acc[4][ni] = __builtin_amdgcn_mfma_f32_16x16x32_bf16(a00, bfr[ni][0], acc[4][ni], 0, 0, 0);
                acc[4][ni] = __builtin_amdgcn_mfma_f32_16x16x32_bf16(a01, bfr[ni][1], acc[4][ni], 0, 0, 0);
                acc[5][ni] = __builtin_amdgcn_mfma_f32_16x16x32_bf16(a10, bfr[ni][0], acc[5][ni], 0, 0, 0);
                acc[5][ni] = __builtin_amdgcn_mfma_f32_16x16x32_bf16(a11, bfr[ni][1], acc[5][ni], 0, 0, 0);
            }
            __builtin_amdgcn_s_setprio(0);
        }
        MEMFENCE;
        __builtin_amdgcn_s_barrier();
        MEMFENCE;
        // ---------------- P3: A frags 6,7 ----------------
        STAGE(tau + 2, 3);
        {
            s16x8 a00 = LDA(6, 0), a01 = LDA(6, 1), a10 = LDA(7, 0), a11 = LDA(7, 1);
            __builtin_amdgcn_s_setprio(1);
            #pragma unroll
            for (int ni = 0; ni < 4; ++ni) {
                acc[6][ni] = __builtin_amdgcn_mfma_f32_16x16x32_bf16(a00, bfr[ni][0], acc[6][ni], 0, 0, 0);
                acc[6][ni] = __builtin_amdgcn_mfma_f32_16x16x32_bf16(a01, bfr[ni][1], acc[6][ni], 0, 0, 0);
                acc[7][ni] = __builtin_amdgcn_mfma_f32_16x16x32_bf16(a10, bfr[ni][0], acc[7][ni], 0, 0, 0);
                acc[7][ni] = __builtin_amdgcn_mfma_f32_16x16x32_bf16(a11, bfr[ni][1], acc[7][ni], 0, 0, 0);
            }
            __builtin_amdgcn_s_setprio(0);
        }
        MEMFENCE;
        __builtin_amdgcn_s_barrier();
        MEMFENCE;
    }

    // ---- epilogue: C write ----
    float* P = part + (size_t)blockIdx.z * ((size_t)M * N);
    #pragma unroll
    for (int mi = 0; mi < 8; ++mi) {
        #pragma unroll
        for (int ni = 0; ni < 4; ++ni) {
            int row = m0 + wr * 128 + mi * 16 + (lane >> 4) * 4;
            int col = n0 + wcn * 64 + ni * 16 + lr;
            #pragma unroll
            for (int r = 0; r < 4; ++r)
                P[(size_t)(row + r) * N + col] = acc[mi][ni][r];
        }
    }
}

// ---------- 4. split-K reduce + bias (+optional bf16 cast) ----------
template<int OUTBF>
__global__ __launch_bounds__(256) void reduce_bias(
        const float* __restrict__ part, const float* __restrict__ bias,
        void* __restrict__ out, int MN, int N, int S) {
    int idx = blockIdx.x * 256 + threadIdx.x;
    if (idx >= MN) return;
    float s = 0.f;
    for (int i = 0; i < S; ++i) s += part[(size_t)i * MN + idx];
    s += bias[idx & (N - 1)];
    if (OUTBF) ((unsigned short*)out)[idx] = f2bf(s);
    else       ((float*)out)[idx] = s;
}

// ---------- 5. heads: cls (softmax over 3) + reg (12) ----------
__global__ __launch_bounds__(256) void heads_kernel(
        const float* __restrict__ h, const float* __restrict__ Wc,
        const float* __restrict__ bc, const float* __restrict__ Wr,
        const float* __restrict__ br, float* __restrict__ out) {
    const int m = blockIdx.x;
    const int t = threadIdx.x;
    __shared__ float red[4][15];
    __shared__ float fin[15];
    const float* hr = h + (size_t)m * 4096;
    float v[15];
    #pragma unroll
    for (int j = 0; j < 15; ++j) v[j] = 0.f;
    for (int k = t; k < 4096; k += 256) {
        float hv = hr[k];
        const float* wc = Wc + k * 3;
        v[0] += hv * wc[0]; v[1] += hv * wc[1]; v[2] += hv * wc[2];
        const float* wr = Wr + k * 12;
        #pragma unroll
        for (int j = 0; j < 12; ++j) v[3 + j] += hv * wr[j];
    }
    const int lane = t & 63, wv = t >> 6;
    #pragma unroll
    for (int j = 0; j < 15; ++j) {
        float x = v[j];
        #pragma unroll
        for (int off = 32; off >= 1; off >>= 1)
            x += __shfl_down(x, off, 64);
        if (lane == 0) red[wv][j] = x;
    }
    __syncthreads();
    if (t < 15) {
        float s = red[0][t] + red[1][t] + red[2][t] + red[3][t];
        s += (t < 3) ? bc[t] : br[t - 3];
        fin[t] = s;
    }
    __syncthreads();
    if (t == 0) {
        float l0 = fin[0], l1 = fin[1], l2 = fin[2];
        float mx = fmaxf(l0, fmaxf(l1, l2));
        float e0 = expf(l0 - mx), e1 = expf(l1 - mx), e2 = expf(l2 - mx);
        float inv = 1.f / (e0 + e1 + e2);
        out[m * 3 + 0] = e0 * inv;
        out[m * 3 + 1] = e1 * inv;
        out[m * 3 + 2] = e2 * inv;
    }
    if (t >= 3 && t < 15) out[3072 + m * 12 + (t - 3)] = fin[t];
}

// ---------- launch ----------
extern "C" void kernel_launch(void* const* d_in, const int* in_sizes, int n_in,
                              void* d_out, int out_size, void* d_ws, size_t ws_size,
                              hipStream_t stream) {
    const float* featmap = (const float*)d_in[0];
    const int*   roi     = (const int*)d_in[1];
    const float* W1      = (const float*)d_in[2];
    const float* b1      = (const float*)d_in[3];
    const float* W2      = (const float*)d_in[4];
    const float* b2      = (const float*)d_in[5];
    const float* Wc      = (const float*)d_in[6];
    const float* bc      = (const float*)d_in[7];
    const float* Wr      = (const float*)d_in[8];
    const float* br      = (const float*)d_in[9];
    float* out = (float*)d_out;

    // workspace layout (bytes)
    char* ws = (char*)d_ws;
    unsigned short* pooled = (unsigned short*)(ws);                  //  51,380,224  [1024][25088] bf16 (k' = b*512+c)
    unsigned short* W1T    = (unsigned short*)(ws + 51380224);       // 205,520,896  [4096][25088] bf16 (k' order)
    float*          part   = (float*)        (ws + 256901120);       //  67,108,864  [4][1024][4096] f32
    unsigned short* h1     = (unsigned short*)(ws + 324009984);      //   8,388,608  [1024][4096] bf16
    float*          hbuf   = (float*)        (ws + 332398592);       //  16,777,216  [1024][4096] f32
    unsigned short* W2T    = (unsigned short*)(ws + 51380224);       // alias of W1T (used after gemm1)
    unsigned short* fmT    = (unsigned short*)(ws + 256901120);      // alias of part (dead before gemm1)

    const int M = 1024, N = 4096, K1 = 25088, K2 = 4096;

    hipFuncSetAttribute((const void*)gemm256,
                        hipFuncAttributeMaxDynamicSharedMemorySize, 131072);

    transpose_fm<<<dim3(132, 16), dim3(32, 8), 0, stream>>>(featmap, fmT);
    pool_kernel2<<<1024, 256, 0, stream>>>(fmT, roi, pooled);
    transpose_w1_perm<<<dim3(64, 8, 49), dim3(32, 8), 0, stream>>>(W1, W1T);
    gemm256<<<dim3(N / 256, M / 256, 4), 512, 131072, stream>>>(pooled, W1T, part, M, N, K1, 98);
    transpose_bf16<<<dim3(4096 / 32, 4096 / 32), dim3(32, 8), 0, stream>>>(W2, W2T, K2, N);
    reduce_bias<1><<<(M * N) / 256, 256, 0, stream>>>(part, b1, h1, M * N, N, 4);
    gemm256<<<dim3(N / 256, M / 256, 4), 512, 131072, stream>>>(h1, W2T, part, M, N, K2, 16);
    reduce_bias<0><<<(M * N) / 256, 256, 0, stream>>>(part, b2, hbuf, M * N, N, 4);
    heads_kernel<<<1024, 256, 0, stream>>>(hbuf, Wc, bc, Wr, br, out);
}

// Round 5
// 579.046 us; speedup vs baseline: 1.8184x; 1.0759x over previous
//
#include <hip/hip_runtime.h>
#include <hip/hip_bf16.h>
#include <cstdint>
#include <cstddef>

// ---------- types ----------
typedef __attribute__((ext_vector_type(4))) float f32x4;
typedef __attribute__((ext_vector_type(8))) short s16x8;

__device__ __forceinline__ unsigned short f2bf(float f) {
    union { float f; unsigned u; } v; v.f = f;
    unsigned u = v.u;
    u += 0x7fffu + ((u >> 16) & 1u);      // round-to-nearest-even
    return (unsigned short)(u >> 16);
}
__device__ __forceinline__ float bf2f(unsigned short u) {
    union { unsigned u; float f; } v; v.u = ((unsigned)u) << 16; return v.f;
}

// =====================================================================
// The whole reference network is LINEAR (no activation between the two
// FC layers; softmax only at the end):
//   out_pre = pooled @ Wbig + bbig,   Wbig = W1 @ W2 @ [Wc|Wr]  (25088x15)
//   bbig    = ((b1 @ W2) + b2) @ [Wc|Wr] + [bc|br]
// So we never run the 25088x4096 / 4096x4096 GEMMs at all.
// k' ordering: pooled[n][bin*512 + c]  <->  W1 row (c*49 + bin).
// =====================================================================

// ---------- 0. featmap transpose: fm[512][4200] f32 -> fmT[4200][512] bf16 ----------
__global__ __launch_bounds__(256) void transpose_fm(
        const float* __restrict__ fm, unsigned short* __restrict__ fmT) {
    __shared__ float tile[32][33];
    int p0 = blockIdx.x * 32, c0 = blockIdx.y * 32;
    int tx = threadIdx.x, ty = threadIdx.y;      // (32,8)
    #pragma unroll
    for (int yy = ty; yy < 32; yy += 8) {
        int p = p0 + tx;
        if (p < 4200) tile[yy][tx] = fm[(size_t)(c0 + yy) * 4200 + p];
    }
    __syncthreads();
    #pragma unroll
    for (int yy = ty; yy < 32; yy += 8) {
        int p = p0 + yy;
        if (p < 4200) fmT[(size_t)p * 512 + c0 + tx] = f2bf(tile[tx][yy]);
    }
}

// ---------- 1. ROI max pooling (channel-last) -> pooled bf16 [1024][bin*512+c] ----------
__global__ __launch_bounds__(256) void pool_kernel2(
        const unsigned short* __restrict__ fmT, const int* __restrict__ roi,
        unsigned short* __restrict__ pooled) {
    const int n = blockIdx.x;
    __shared__ int hs[7], he[7], wss[7], wee[7];
    if (threadIdx.x == 0) {
        int x0 = roi[n*4+0] / 16, y0 = roi[n*4+1] / 16;
        int x1 = roi[n*4+2] / 16, y1 = roi[n*4+3] / 16;
        if (x1 - x0 <= 1) { if (x1 < 84) x1 += 1; else x0 -= 1; }
        if (y1 - y0 <= 1) { if (y1 < 50) y1 += 1; else y0 -= 1; }
        int xs = min(max(x0, 0), 84), xe = min(max(x1, 0), 84);
        int ys = min(max(y0, 0), 50), ye = min(max(y1, 0), 50);
        int Lx = xe - xs, Ly = ye - ys;
        #pragma unroll
        for (int i = 0; i < 7; ++i) {
            int b0 = ys + (i * Ly) / 7, b1 = ys + ((i + 1) * Ly + 6) / 7;
            hs[i] = b0; he[i] = min(b1, b0 + 5);          // KMAX=5 window cap
            int c0 = xs + (i * Lx) / 7, c1 = xs + ((i + 1) * Lx + 6) / 7;
            wss[i] = c0; wee[i] = min(c1, c0 + 5);
        }
    }
    __syncthreads();
    const int t = threadIdx.x;                    // channel pair 2t, 2t+1
    unsigned short* orow = pooled + (size_t)n * 25088;
    for (int bi = 0; bi < 7; ++bi) {
        const int h0 = hs[bi], h1 = he[bi];
        for (int bj = 0; bj < 7; ++bj) {
            const int w0 = wss[bj], w1 = wee[bj];
            float m0 = -1e30f, m1 = -1e30f;
            for (int hh = h0; hh < h1; ++hh) {
                const unsigned short* base = fmT + (size_t)(hh * 84) * 512 + 2 * t;
                for (int ww = w0; ww < w1; ++ww) {
                    ushort2 v = *(const ushort2*)(base + ww * 512);
                    m0 = fmaxf(m0, bf2f(v.x));
                    m1 = fmaxf(m1, bf2f(v.y));
                }
            }
            ushort2 o; o.x = f2bf(m0); o.y = f2bf(m1);
            *(ushort2*)(orow + (bi * 7 + bj) * 512 + 2 * t) = o;
        }
    }
}

// ---------- 2. Wf = W2 @ [Wc|Wr]  (4096x15 f32) ; bf = b2@[Wc|Wr] + [bc|br] ----------
// blocks 0..511: 8 k-rows each (1 wave per row).  block 512: bias.
__global__ __launch_bounds__(512) void fuse_w2(
        const float* __restrict__ W2, const float* __restrict__ Wc,
        const float* __restrict__ bc, const float* __restrict__ Wr,
        const float* __restrict__ br, const float* __restrict__ b2,
        float* __restrict__ Wf, float* __restrict__ bfv) {
    __shared__ float wch[15360];                 // 1024 i-rows x 15
    const int t = threadIdx.x;
    const int blk = blockIdx.x;
    if (blk < 512) {
        const int lane = t & 63, wave = t >> 6;
        const int k = blk * 8 + wave;
        const float* w2row = W2 + (size_t)k * 4096;
        float acc[15];
        #pragma unroll
        for (int j = 0; j < 15; ++j) acc[j] = 0.f;
        for (int ch = 0; ch < 4; ++ch) {
            const int ibase = ch * 1024;
            __syncthreads();
            for (int e = t; e < 15360; e += 512) {
                int i = ibase + e / 15, j = e % 15;
                wch[e] = (j < 3) ? Wc[i * 3 + j] : Wr[i * 12 + (j - 3)];
            }
            __syncthreads();
            for (int u = 0; u < 16; ++u) {
                int i = u * 64 + lane;
                float w2v = w2row[ibase + i];
                #pragma unroll
                for (int j = 0; j < 15; ++j)
                    acc[j] += w2v * wch[i * 15 + j];
            }
        }
        #pragma unroll
        for (int j = 0; j < 15; ++j) {
            float x = acc[j];
            #pragma unroll
            for (int off = 32; off >= 1; off >>= 1) x += __shfl_xor(x, off, 64);
            acc[j] = x;
        }
        if (lane == 0) {
            #pragma unroll
            for (int j = 0; j < 15; ++j) Wf[(size_t)k * 15 + j] = acc[j];
        }
    } else {
        // bf[j] = sum_i b2[i]*Wcat[i][j] + bcat[j]
        float acc[15];
        #pragma unroll
        for (int j = 0; j < 15; ++j) acc[j] = 0.f;
        for (int i = t; i < 4096; i += 512) {
            float bv = b2[i];
            #pragma unroll
            for (int j = 0; j < 15; ++j)
                acc[j] += bv * ((j < 3) ? Wc[i * 3 + j] : Wr[i * 12 + (j - 3)]);
        }
        const int lane = t & 63, wave = t >> 6;
        __shared__ float red[8][15];
        #pragma unroll
        for (int j = 0; j < 15; ++j) {
            float x = acc[j];
            #pragma unroll
            for (int off = 32; off >= 1; off >>= 1) x += __shfl_xor(x, off, 64);
            acc[j] = x;
        }
        if (lane == 0) {
            #pragma unroll
            for (int j = 0; j < 15; ++j) red[wave][j] = acc[j];
        }
        __syncthreads();
        if (t < 15) {
            float s = 0.f;
            #pragma unroll
            for (int w = 0; w < 8; ++w) s += red[w][t];
            s += (t < 3) ? bc[t] : br[t - 3];
            bfv[t] = s;
        }
    }
}

// ---------- 3. WbigT[j][p'] = (W1 @ Wf)^T  bf16 [16][25088] ; bbig ----------
// blocks 0..3135: 8 p'-rows each (1 wave per row); row perm p' -> W1 row c*49+bin.
// block 3136: bbig[j] = b1@Wf + bf.
__global__ __launch_bounds__(512) void wbig_kernel(
        const float* __restrict__ W1, const float* __restrict__ Wf,
        const float* __restrict__ bfv, const float* __restrict__ b1,
        unsigned short* __restrict__ WbigT, float* __restrict__ bbig) {
    __shared__ float wch[15360];
    const int t = threadIdx.x;
    const int blk = blockIdx.x;
    if (blk < 3136) {
        const int lane = t & 63, wave = t >> 6;
        const int p = blk * 8 + wave;            // p' (k' index)
        const int bin = p >> 9, c = p & 511;
        const float* w1row = W1 + ((size_t)c * 49 + bin) * 4096;
        float acc[15];
        #pragma unroll
        for (int j = 0; j < 15; ++j) acc[j] = 0.f;
        for (int ch = 0; ch < 4; ++ch) {
            __syncthreads();
            for (int e = t; e < 15360; e += 512)
                wch[e] = Wf[ch * 15360 + e];     // coalesced: Wf is contiguous
            __syncthreads();
            const int ibase = ch * 1024;
            for (int u = 0; u < 16; ++u) {
                int i = u * 64 + lane;
                float w1v = w1row[ibase + i];
                #pragma unroll
                for (int j = 0; j < 15; ++j)
                    acc[j] += w1v * wch[i * 15 + j];
            }
        }
        #pragma unroll
        for (int j = 0; j < 15; ++j) {
            float x = acc[j];
            #pragma unroll
            for (int off = 32; off >= 1; off >>= 1) x += __shfl_xor(x, off, 64);
            if (lane == j) WbigT[(size_t)j * 25088 + p] = f2bf(x);
        }
    } else {
        float acc[15];
        #pragma unroll
        for (int j = 0; j < 15; ++j) acc[j] = 0.f;
        for (int i = t; i < 4096; i += 512) {
            float bv = b1[i];
            #pragma unroll
            for (int j = 0; j < 15; ++j) acc[j] += bv * Wf[(size_t)i * 15 + j];
        }
        const int lane = t & 63, wave = t >> 6;
        __shared__ float red[8][15];
        #pragma unroll
        for (int j = 0; j < 15; ++j) {
            float x = acc[j];
            #pragma unroll
            for (int off = 32; off >= 1; off >>= 1) x += __shfl_xor(x, off, 64);
            acc[j] = x;
        }
        if (lane == 0) {
            #pragma unroll
            for (int j = 0; j < 15; ++j) red[wave][j] = acc[j];
        }
        __syncthreads();
        if (t < 16) {
            float s = 0.f;
            if (t < 15) {
                #pragma unroll
                for (int w = 0; w < 8; ++w) s += red[w][t];
                s += bfv[t];
            }
            bbig[t] = s;                         // bbig[15] = 0
        }
    }
}

// ---------- 4. final GEMM: pooled[1024][25088] @ WbigT^T -> partial[8][1024][16] ----------
// grid (64 m-tiles, 8 k-splits), 256 thr = 4 waves; waves interleave the 98
// K-steps of this block's 3136-k span; LDS reduce across waves.
// MFMA 16x16x32 fragment layout identical to the round-2..4 verified GEMM.
__global__ __launch_bounds__(256) void final_gemm(
        const unsigned short* __restrict__ pooled,
        const unsigned short* __restrict__ WbigT,
        float* __restrict__ partial) {
    const int t = threadIdx.x, lane = t & 63, wave = t >> 6;
    const int m0 = blockIdx.x * 16, kz = blockIdx.y;
    const int lr = lane & 15, lks = lane >> 4;
    f32x4 acc = {0.f, 0.f, 0.f, 0.f};
    const unsigned short* arow = pooled + (size_t)(m0 + lr) * 25088 + kz * 3136 + lks * 8;
    const unsigned short* brow = WbigT + (size_t)lr * 25088 + kz * 3136 + lks * 8;
    for (int s = wave; s < 98; s += 4) {
        s16x8 a = *(const s16x8*)(arow + s * 32);
        s16x8 b = *(const s16x8*)(brow + s * 32);
        acc = __builtin_amdgcn_mfma_f32_16x16x32_bf16(a, b, acc, 0, 0, 0);
    }
    __shared__ float red[4][64][4];
    #pragma unroll
    for (int r = 0; r < 4; ++r) red[wave][lane][r] = acc[r];
    __syncthreads();
    if (wave == 0) {
        #pragma unroll
        for (int r = 0; r < 4; ++r) {
            float s = red[0][lane][r] + red[1][lane][r] + red[2][lane][r] + red[3][lane][r];
            int row = m0 + (lane >> 4) * 4 + r;
            partial[((size_t)kz * 1024 + row) * 16 + (lane & 15)] = s;
        }
    }
}

// ---------- 5. finalize: sum 8 partials + bbig, softmax(3), write out ----------
__global__ __launch_bounds__(256) void finalize_kernel(
        const float* __restrict__ partial, const float* __restrict__ bbig,
        float* __restrict__ out) {
    const int m = blockIdx.x * 256 + threadIdx.x;   // 0..1023
    float v[15];
    #pragma unroll
    for (int j = 0; j < 15; ++j) v[j] = bbig[j];
    for (int kz = 0; kz < 8; ++kz) {
        const float* p = partial + ((size_t)kz * 1024 + m) * 16;
        #pragma unroll
        for (int j = 0; j < 15; ++j) v[j] += p[j];
    }
    float mx = fmaxf(v[0], fmaxf(v[1], v[2]));
    float e0 = expf(v[0] - mx), e1 = expf(v[1] - mx), e2 = expf(v[2] - mx);
    float inv = 1.f / (e0 + e1 + e2);
    out[m * 3 + 0] = e0 * inv;
    out[m * 3 + 1] = e1 * inv;
    out[m * 3 + 2] = e2 * inv;
    #pragma unroll
    for (int j = 3; j < 15; ++j) out[3072 + m * 12 + (j - 3)] = v[j];
}

// ---------- launch ----------
extern "C" void kernel_launch(void* const* d_in, const int* in_sizes, int n_in,
                              void* d_out, int out_size, void* d_ws, size_t ws_size,
                              hipStream_t stream) {
    const float* featmap = (const float*)d_in[0];
    const int*   roi     = (const int*)d_in[1];
    const float* W1      = (const float*)d_in[2];
    const float* b1      = (const float*)d_in[3];
    const float* W2      = (const float*)d_in[4];
    const float* b2      = (const float*)d_in[5];
    const float* Wc      = (const float*)d_in[6];
    const float* bc      = (const float*)d_in[7];
    const float* Wr      = (const float*)d_in[8];
    const float* br      = (const float*)d_in[9];
    float* out = (float*)d_out;

    // workspace layout (bytes, all 16-aligned)
    char* ws = (char*)d_ws;
    unsigned short* pooled  = (unsigned short*)(ws);                 // 51,380,224  [1024][25088] bf16
    unsigned short* fmT     = (unsigned short*)(ws + 51380224);      //  4,300,800  [4200][512] bf16
    float*          Wf      = (float*)        (ws + 55681024);       //    245,760  [4096][15] f32
    float*          bfv     = (float*)        (ws + 55926784);       //         64
    float*          bbig    = (float*)        (ws + 55926848);       //         64  [16]
    unsigned short* WbigT   = (unsigned short*)(ws + 55926912);      //    802,816  [16][25088] bf16
    float*          partial = (float*)        (ws + 56729728);       //    524,288  [8][1024][16] f32

    transpose_fm<<<dim3(132, 16), dim3(32, 8), 0, stream>>>(featmap, fmT);
    pool_kernel2<<<1024, 256, 0, stream>>>(fmT, roi, pooled);
    fuse_w2<<<513, 512, 0, stream>>>(W2, Wc, bc, Wr, br, b2, Wf, bfv);
    wbig_kernel<<<3137, 512, 0, stream>>>(W1, Wf, bfv, b1, WbigT, bbig);
    final_gemm<<<dim3(64, 8), 256, 0, stream>>>(pooled, WbigT, partial);
    finalize_kernel<<<4, 256, 0, stream>>>(partial, bbig, out);
}

// Round 6
// 426.633 us; speedup vs baseline: 2.4680x; 1.3572x over previous
//
#include <hip/hip_runtime.h>
#include <hip/hip_bf16.h>
#include <cstdint>
#include <cstddef>

// ---------- types ----------
typedef __attribute__((ext_vector_type(4))) float f32x4;
typedef __attribute__((ext_vector_type(8))) short s16x8;

__device__ __forceinline__ unsigned short f2bf(float f) {
    union { float f; unsigned u; } v; v.f = f;
    unsigned u = v.u;
    u += 0x7fffu + ((u >> 16) & 1u);      // round-to-nearest-even
    return (unsigned short)(u >> 16);
}
__device__ __forceinline__ float bf2f(unsigned short u) {
    union { unsigned u; float f; } v; v.u = ((unsigned)u) << 16; return v.f;
}

// =====================================================================
// Network is LINEAR: out_pre = pooled @ Wbig + bbig,
//   Wbig = W1 @ W2 @ [Wc|Wr],  bbig = ((b1@W2)+b2)@[Wc|Wr] + [bc|br].
// Skinny GEMMs are done with lane-per-row + LDS-staged A + scalar-load B
// (B is [K][16]-padded so the per-i row is one s_load_dwordx16).
// k' ordering: pooled[n][bin*512+c] <-> W1 row (c*49+bin).
// =====================================================================

// ---------- 0. featmap transpose: fm[512][4200] f32 -> fmT[4200][512] bf16 ----------
__global__ __launch_bounds__(256) void transpose_fm(
        const float* __restrict__ fm, unsigned short* __restrict__ fmT) {
    __shared__ float tile[32][33];
    int p0 = blockIdx.x * 32, c0 = blockIdx.y * 32;
    int tx = threadIdx.x, ty = threadIdx.y;      // (32,8)
    #pragma unroll
    for (int yy = ty; yy < 32; yy += 8) {
        int p = p0 + tx;
        if (p < 4200) tile[yy][tx] = fm[(size_t)(c0 + yy) * 4200 + p];
    }
    __syncthreads();
    #pragma unroll
    for (int yy = ty; yy < 32; yy += 8) {
        int p = p0 + yy;
        if (p < 4200) fmT[(size_t)p * 512 + c0 + tx] = f2bf(tile[tx][yy]);
    }
}

// ---------- 1. ROI max pooling (channel-last) -> pooled bf16 [1024][bin*512+c] ----------
__global__ __launch_bounds__(256) void pool_kernel2(
        const unsigned short* __restrict__ fmT, const int* __restrict__ roi,
        unsigned short* __restrict__ pooled) {
    const int n = blockIdx.x;
    __shared__ int hs[7], he[7], wss[7], wee[7];
    if (threadIdx.x == 0) {
        int x0 = roi[n*4+0] / 16, y0 = roi[n*4+1] / 16;
        int x1 = roi[n*4+2] / 16, y1 = roi[n*4+3] / 16;
        if (x1 - x0 <= 1) { if (x1 < 84) x1 += 1; else x0 -= 1; }
        if (y1 - y0 <= 1) { if (y1 < 50) y1 += 1; else y0 -= 1; }
        int xs = min(max(x0, 0), 84), xe = min(max(x1, 0), 84);
        int ys = min(max(y0, 0), 50), ye = min(max(y1, 0), 50);
        int Lx = xe - xs, Ly = ye - ys;
        #pragma unroll
        for (int i = 0; i < 7; ++i) {
            int b0 = ys + (i * Ly) / 7, b1 = ys + ((i + 1) * Ly + 6) / 7;
            hs[i] = b0; he[i] = min(b1, b0 + 5);          // KMAX=5 window cap
            int c0 = xs + (i * Lx) / 7, c1 = xs + ((i + 1) * Lx + 6) / 7;
            wss[i] = c0; wee[i] = min(c1, c0 + 5);
        }
    }
    __syncthreads();
    const int t = threadIdx.x;                    // channel pair 2t, 2t+1
    unsigned short* orow = pooled + (size_t)n * 25088;
    for (int bi = 0; bi < 7; ++bi) {
        const int h0 = hs[bi], h1 = he[bi];
        for (int bj = 0; bj < 7; ++bj) {
            const int w0 = wss[bj], w1 = wee[bj];
            float m0 = -1e30f, m1 = -1e30f;
            for (int hh = h0; hh < h1; ++hh) {
                const unsigned short* base = fmT + (size_t)(hh * 84) * 512 + 2 * t;
                for (int ww = w0; ww < w1; ++ww) {
                    ushort2 v = *(const ushort2*)(base + ww * 512);
                    m0 = fmaxf(m0, bf2f(v.x));
                    m1 = fmaxf(m1, bf2f(v.y));
                }
            }
            ushort2 o; o.x = f2bf(m0); o.y = f2bf(m1);
            *(ushort2*)(orow + (bi * 7 + bj) * 512 + 2 * t) = o;
        }
    }
}

// ---------- 2. Wcat16[i][16] = [Wc | Wr | 0] ----------
__global__ __launch_bounds__(256) void prep_wcat(
        const float* __restrict__ Wc, const float* __restrict__ Wr,
        float* __restrict__ Wcat16) {
    int idx = blockIdx.x * 256 + threadIdx.x;    // 0..65535
    int i = idx >> 4, j = idx & 15;
    float v = (j < 3) ? Wc[i * 3 + j] : (j < 15) ? Wr[i * 12 + (j - 3)] : 0.f;
    Wcat16[idx] = v;
}

// ---------- 3. skinny GEMM: out[p][16] = A[arow(p)][:] @ B16 (i-split partials) ----
// lane owns one output row p; A staged [256][32] -> LDS [256][33] (2-way, free);
// B16 row per i is wave-uniform -> scalar loads.  grid (R/256, NSPLIT).
template<int PERM>
__global__ __launch_bounds__(256) void skinny_gemm(
        const float* __restrict__ A, const float* __restrict__ B16,
        float* __restrict__ partial, int isplit) {
    __shared__ float lds[256][33];
    const int t = threadIdx.x;
    const int p0 = blockIdx.x * 256;
    const int i0 = blockIdx.y * isplit;
    float acc[15];
    #pragma unroll
    for (int j = 0; j < 15; ++j) acc[j] = 0.f;

    for (int ch = 0; ch < isplit; ch += 32) {
        __syncthreads();
        #pragma unroll
        for (int g = 0; g < 8; ++g) {
            int r = g * 32 + (t >> 3);
            int pr = p0 + r;
            int ar = PERM ? ((pr & 511) * 49 + (pr >> 9)) : pr;
            int i4 = (t & 7) * 4;
            float4 v = *(const float4*)(A + (size_t)ar * 4096 + i0 + ch + i4);
            lds[r][i4 + 0] = v.x; lds[r][i4 + 1] = v.y;
            lds[r][i4 + 2] = v.z; lds[r][i4 + 3] = v.w;
        }
        __syncthreads();
        const float* bw = B16 + (size_t)(i0 + ch) * 16;   // wave-uniform
        #pragma unroll
        for (int ii = 0; ii < 32; ++ii) {
            float av = lds[t][ii];
            #pragma unroll
            for (int j = 0; j < 15; ++j)
                acc[j] = fmaf(av, bw[ii * 16 + j], acc[j]);
        }
    }
    float* op = partial + ((size_t)blockIdx.y * gridDim.x * 256 + p0 + t) * 16;
    float4 o0 = {acc[0], acc[1], acc[2], acc[3]};
    float4 o1 = {acc[4], acc[5], acc[6], acc[7]};
    float4 o2 = {acc[8], acc[9], acc[10], acc[11]};
    float4 o3 = {acc[12], acc[13], acc[14], 0.f};
    ((float4*)op)[0] = o0; ((float4*)op)[1] = o1;
    ((float4*)op)[2] = o2; ((float4*)op)[3] = o3;
}

// ---------- 4. reduce partial1 -> Wf16 [4096][16]; block 256 computes bfv ----------
__global__ __launch_bounds__(256) void reduce_wf(
        const float* __restrict__ partial1, const float* __restrict__ b2,
        const float* __restrict__ Wcat16, const float* __restrict__ bc,
        const float* __restrict__ br, float* __restrict__ Wf16,
        float* __restrict__ bfv) {
    const int t = threadIdx.x;
    if (blockIdx.x < 256) {
        int idx = blockIdx.x * 256 + t;          // over 65536
        float s = 0.f;
        #pragma unroll
        for (int sp = 0; sp < 16; ++sp) s += partial1[sp * 65536 + idx];
        Wf16[idx] = s;
    } else {
        float acc[15];
        #pragma unroll
        for (int j = 0; j < 15; ++j) acc[j] = 0.f;
        for (int i = t; i < 4096; i += 256) {
            float bv = b2[i];
            #pragma unroll
            for (int j = 0; j < 15; ++j) acc[j] += bv * Wcat16[i * 16 + j];
        }
        const int lane = t & 63, wv = t >> 6;
        __shared__ float red[4][15];
        #pragma unroll
        for (int j = 0; j < 15; ++j) {
            float x = acc[j];
            #pragma unroll
            for (int off = 32; off >= 1; off >>= 1) x += __shfl_xor(x, off, 64);
            if (lane == 0) red[wv][j] = x;
        }
        __syncthreads();
        if (t < 15)
            bfv[t] = red[0][t] + red[1][t] + red[2][t] + red[3][t]
                   + ((t < 3) ? bc[t] : br[t - 3]);
    }
}

// ---------- 5. reduce partial2 -> WbigT bf16 [16][25088]; block 98 computes bbig ----
__global__ __launch_bounds__(256) void reduce_wbig(
        const float* __restrict__ partial2, const float* __restrict__ Wf16,
        const float* __restrict__ bfv, const float* __restrict__ b1,
        unsigned short* __restrict__ WbigT, float* __restrict__ bbig) {
    const int t = threadIdx.x;
    if (blockIdx.x < 98) {
        const int p = blockIdx.x * 256 + t;
        float sj[16];
        #pragma unroll
        for (int j = 0; j < 16; ++j) sj[j] = 0.f;
        #pragma unroll
        for (int sp = 0; sp < 8; ++sp) {
            const float4* pp = (const float4*)(partial2 + ((size_t)sp * 25088 + p) * 16);
            float4 a = pp[0], b = pp[1], c = pp[2], d = pp[3];
            sj[0] += a.x; sj[1] += a.y; sj[2]  += a.z; sj[3]  += a.w;
            sj[4] += b.x; sj[5] += b.y; sj[6]  += b.z; sj[7]  += b.w;
            sj[8] += c.x; sj[9] += c.y; sj[10] += c.z; sj[11] += c.w;
            sj[12] += d.x; sj[13] += d.y; sj[14] += d.z; sj[15] += d.w;
        }
        #pragma unroll
        for (int j = 0; j < 16; ++j)             // coalesced over p
            WbigT[(size_t)j * 25088 + p] = f2bf(sj[j]);
    } else {
        float acc[15];
        #pragma unroll
        for (int j = 0; j < 15; ++j) acc[j] = 0.f;
        for (int i = t; i < 4096; i += 256) {
            float bv = b1[i];
            #pragma unroll
            for (int j = 0; j < 15; ++j) acc[j] += bv * Wf16[i * 16 + j];
        }
        const int lane = t & 63, wv = t >> 6;
        __shared__ float red[4][15];
        #pragma unroll
        for (int j = 0; j < 15; ++j) {
            float x = acc[j];
            #pragma unroll
            for (int off = 32; off >= 1; off >>= 1) x += __shfl_xor(x, off, 64);
            if (lane == 0) red[wv][j] = x;
        }
        __syncthreads();
        if (t < 16) {
            float s = 0.f;
            if (t < 15)
                s = red[0][t] + red[1][t] + red[2][t] + red[3][t] + bfv[t];
            bbig[t] = s;
        }
    }
}

// ---------- 6. final GEMM: pooled[1024][25088] @ WbigT^T -> partialG[8][1024][16] ----
__global__ __launch_bounds__(256) void final_gemm(
        const unsigned short* __restrict__ pooled,
        const unsigned short* __restrict__ WbigT,
        float* __restrict__ partialG) {
    const int t = threadIdx.x, lane = t & 63, wave = t >> 6;
    const int m0 = blockIdx.x * 16, kz = blockIdx.y;
    const int lr = lane & 15, lks = lane >> 4;
    f32x4 acc = {0.f, 0.f, 0.f, 0.f};
    const unsigned short* arow = pooled + (size_t)(m0 + lr) * 25088 + kz * 3136 + lks * 8;
    const unsigned short* brow = WbigT + (size_t)lr * 25088 + kz * 3136 + lks * 8;
    for (int s = wave; s < 98; s += 4) {
        s16x8 a = *(const s16x8*)(arow + s * 32);
        s16x8 b = *(const s16x8*)(brow + s * 32);
        acc = __builtin_amdgcn_mfma_f32_16x16x32_bf16(a, b, acc, 0, 0, 0);
    }
    __shared__ float red[4][64][4];
    #pragma unroll
    for (int r = 0; r < 4; ++r) red[wave][lane][r] = acc[r];
    __syncthreads();
    if (wave == 0) {
        #pragma unroll
        for (int r = 0; r < 4; ++r) {
            float s = red[0][lane][r] + red[1][lane][r] + red[2][lane][r] + red[3][lane][r];
            int row = m0 + (lane >> 4) * 4 + r;
            partialG[((size_t)kz * 1024 + row) * 16 + (lane & 15)] = s;
        }
    }
}

// ---------- 7. finalize: sum 8 partials + bbig, softmax(3), write out ----------
__global__ __launch_bounds__(256) void finalize_kernel(
        const float* __restrict__ partialG, const float* __restrict__ bbig,
        float* __restrict__ out) {
    const int m = blockIdx.x * 256 + threadIdx.x;   // 0..1023
    float v[15];
    #pragma unroll
    for (int j = 0; j < 15; ++j) v[j] = bbig[j];
    for (int kz = 0; kz < 8; ++kz) {
        const float* p = partialG + ((size_t)kz * 1024 + m) * 16;
        #pragma unroll
        for (int j = 0; j < 15; ++j) v[j] += p[j];
    }
    float mx = fmaxf(v[0], fmaxf(v[1], v[2]));
    float e0 = expf(v[0] - mx), e1 = expf(v[1] - mx), e2 = expf(v[2] - mx);
    float inv = 1.f / (e0 + e1 + e2);
    out[m * 3 + 0] = e0 * inv;
    out[m * 3 + 1] = e1 * inv;
    out[m * 3 + 2] = e2 * inv;
    #pragma unroll
    for (int j = 3; j < 15; ++j) out[3072 + m * 12 + (j - 3)] = v[j];
}

// ---------- launch ----------
extern "C" void kernel_launch(void* const* d_in, const int* in_sizes, int n_in,
                              void* d_out, int out_size, void* d_ws, size_t ws_size,
                              hipStream_t stream) {
    const float* featmap = (const float*)d_in[0];
    const int*   roi     = (const int*)d_in[1];
    const float* W1      = (const float*)d_in[2];
    const float* b1      = (const float*)d_in[3];
    const float* W2      = (const float*)d_in[4];
    const float* b2      = (const float*)d_in[5];
    const float* Wc      = (const float*)d_in[6];
    const float* bc      = (const float*)d_in[7];
    const float* Wr      = (const float*)d_in[8];
    const float* br      = (const float*)d_in[9];
    float* out = (float*)d_out;

    // workspace layout (bytes, 16-aligned)
    char* ws = (char*)d_ws;
    unsigned short* pooled   = (unsigned short*)(ws);                // 51,380,224  [1024][25088] bf16
    unsigned short* fmT      = (unsigned short*)(ws + 51380224);     //  4,300,800  [4200][512] bf16
    float*          Wcat16   = (float*)        (ws + 55681024);      //    262,144  [4096][16] f32
    float*          Wf16     = (float*)        (ws + 55943168);      //    262,144  [4096][16] f32
    float*          bfv      = (float*)        (ws + 56205312);      //         64
    float*          bbig     = (float*)        (ws + 56205376);      //         64  [16]
    float*          partial1 = (float*)        (ws + 56205440);      //  4,194,304  [16][4096][16] f32
    float*          partial2 = (float*)        (ws + 60399744);      // 12,845,056  [8][25088][16] f32
    unsigned short* WbigT    = (unsigned short*)(ws + 73244800);     //    802,816  [16][25088] bf16
    float*          partialG = (float*)        (ws + 74047616);      //    524,288  [8][1024][16] f32

    transpose_fm<<<dim3(132, 16), dim3(32, 8), 0, stream>>>(featmap, fmT);
    pool_kernel2<<<1024, 256, 0, stream>>>(fmT, roi, pooled);
    prep_wcat<<<256, 256, 0, stream>>>(Wc, Wr, Wcat16);
    skinny_gemm<0><<<dim3(16, 16), 256, 0, stream>>>(W2, Wcat16, partial1, 256);
    reduce_wf<<<257, 256, 0, stream>>>(partial1, b2, Wcat16, bc, br, Wf16, bfv);
    skinny_gemm<1><<<dim3(98, 8), 256, 0, stream>>>(W1, Wf16, partial2, 512);
    reduce_wbig<<<99, 256, 0, stream>>>(partial2, Wf16, bfv, b1, WbigT, bbig);
    final_gemm<<<dim3(64, 8), 256, 0, stream>>>(pooled, WbigT, partialG);
    finalize_kernel<<<4, 256, 0, stream>>>(partialG, bbig, out);
}

// Round 7
// 287.446 us; speedup vs baseline: 3.6630x; 1.4842x over previous
//
#include <hip/hip_runtime.h>
#include <hip/hip_bf16.h>
#include <cstdint>
#include <cstddef>

// ---------- types ----------
typedef __attribute__((ext_vector_type(4))) float f32x4;
typedef __attribute__((ext_vector_type(8))) short s16x8;

__device__ __forceinline__ unsigned short f2bf(float f) {
    union { float f; unsigned u; } v; v.f = f;
    unsigned u = v.u;
    u += 0x7fffu + ((u >> 16) & 1u);      // round-to-nearest-even
    return (unsigned short)(u >> 16);
}
__device__ __forceinline__ float bf2f(unsigned short u) {
    union { unsigned u; float f; } v; v.u = ((unsigned)u) << 16; return v.f;
}
__device__ __forceinline__ float lo_f(unsigned v) {   // low bf16 -> f32 (exact)
    union { unsigned u; float f; } w; w.u = v << 16; return w.f;
}
__device__ __forceinline__ float hi_f(unsigned v) {   // high bf16 -> f32 (exact)
    union { unsigned u; float f; } w; w.u = v & 0xffff0000u; return w.f;
}

// =====================================================================
// Network is LINEAR: out_pre = pooled @ Wbig + bbig,
//   Wbig = W1 @ W2 @ [Wc|Wr],  bbig = ((b1@W2)+b2)@[Wc|Wr] + [bc|br].
// pooled k' ordering: pooled[n][bin*512+c] <-> W1 row (c*49+bin).
// Skinny GEMMs read A LINEARLY (contiguous rows); the k'-permutation is
// applied at the tiny WbigT write (reduce_wbig).
// =====================================================================

// ---------- 0. featmap transpose: fm[512][4200] f32 -> fmT[4200][512] bf16 ----------
__global__ __launch_bounds__(256) void transpose_fm(
        const float* __restrict__ fm, unsigned short* __restrict__ fmT) {
    __shared__ float tile[32][33];
    int p0 = blockIdx.x * 32, c0 = blockIdx.y * 32;
    int tx = threadIdx.x, ty = threadIdx.y;      // (32,8)
    #pragma unroll
    for (int yy = ty; yy < 32; yy += 8) {
        int p = p0 + tx;
        if (p < 4200) tile[yy][tx] = fm[(size_t)(c0 + yy) * 4200 + p];
    }
    __syncthreads();
    #pragma unroll
    for (int yy = ty; yy < 32; yy += 8) {
        int p = p0 + yy;
        if (p < 4200) fmT[(size_t)p * 512 + c0 + tx] = f2bf(tile[tx][yy]);
    }
}

// ---------- 1. ROI max pooling, latency-batched 5x5 clamped windows ----------
// Windows are non-empty and span<=5; clamped duplicate reads are idempotent
// for max, so we always issue 25 independent loads per bin (one drain, not 25).
__global__ __launch_bounds__(256) void pool3(
        const unsigned short* __restrict__ fmT, const int* __restrict__ roi,
        unsigned short* __restrict__ pooled) {
    const int n = blockIdx.x;
    __shared__ int hoff[7][5];   // clamped h * (84*512)  element offsets
    __shared__ int woff[7][5];   // clamped w * 512
    if (threadIdx.x == 0) {
        int x0 = roi[n*4+0] / 16, y0 = roi[n*4+1] / 16;
        int x1 = roi[n*4+2] / 16, y1 = roi[n*4+3] / 16;
        if (x1 - x0 <= 1) { if (x1 < 84) x1 += 1; else x0 -= 1; }
        if (y1 - y0 <= 1) { if (y1 < 50) y1 += 1; else y0 -= 1; }
        int xs = min(max(x0, 0), 84), xe = min(max(x1, 0), 84);
        int ys = min(max(y0, 0), 50), ye = min(max(y1, 0), 50);
        int Lx = xe - xs, Ly = ye - ys;
        #pragma unroll
        for (int i = 0; i < 7; ++i) {
            int b0 = ys + (i * Ly) / 7, b1 = ys + ((i + 1) * Ly + 6) / 7;
            int c0 = xs + (i * Lx) / 7, c1 = xs + ((i + 1) * Lx + 6) / 7;
            #pragma unroll
            for (int q = 0; q < 5; ++q) {
                hoff[i][q] = min(b0 + q, b1 - 1) * 43008;
                woff[i][q] = min(c0 + q, c1 - 1) * 512;
            }
        }
    }
    __syncthreads();
    const int t = threadIdx.x;
    const unsigned short* base = fmT + 2 * t;
    unsigned short* orow = pooled + (size_t)n * 25088;
    for (int bi = 0; bi < 7; ++bi) {
        int ho0 = hoff[bi][0], ho1 = hoff[bi][1], ho2 = hoff[bi][2],
            ho3 = hoff[bi][3], ho4 = hoff[bi][4];
        for (int bj = 0; bj < 7; ++bj) {
            unsigned v[25];
            #pragma unroll
            for (int r = 0; r < 5; ++r) {
                int wo = woff[bj][r];
                v[r*5+0] = *(const unsigned*)(base + ho0 + wo);
                v[r*5+1] = *(const unsigned*)(base + ho1 + wo);
                v[r*5+2] = *(const unsigned*)(base + ho2 + wo);
                v[r*5+3] = *(const unsigned*)(base + ho3 + wo);
                v[r*5+4] = *(const unsigned*)(base + ho4 + wo);
            }
            float m0 = lo_f(v[0]), m1 = hi_f(v[0]);
            #pragma unroll
            for (int q = 1; q < 25; ++q) {
                m0 = fmaxf(m0, lo_f(v[q]));
                m1 = fmaxf(m1, hi_f(v[q]));
            }
            ushort2 o; o.x = f2bf(m0); o.y = f2bf(m1);
            *(ushort2*)(orow + (bi * 7 + bj) * 512 + 2 * t) = o;
        }
    }
}

// ---------- 2. Wcat16[i][16] = [Wc | Wr | 0] ----------
__global__ __launch_bounds__(256) void prep_wcat(
        const float* __restrict__ Wc, const float* __restrict__ Wr,
        float* __restrict__ Wcat16) {
    int idx = blockIdx.x * 256 + threadIdx.x;    // 0..65535
    int i = idx >> 4, j = idx & 15;
    float v = (j < 3) ? Wc[i * 3 + j] : (j < 15) ? Wr[i * 12 + (j - 3)] : 0.f;
    Wcat16[idx] = v;
}

// ---------- 3. skinny GEMM: out[p][16] = A[p][:] @ B16 (i-split partials) ----------
// lane owns one output row p (LINEAR); A staged [256][32] -> LDS [256][33];
// B16 row per i is wave-uniform -> scalar loads.  grid (R/256, NSPLIT).
__global__ __launch_bounds__(256) void skinny_gemm(
        const float* __restrict__ A, const float* __restrict__ B16,
        float* __restrict__ partial, int isplit) {
    __shared__ float lds[256][33];
    const int t = threadIdx.x;
    const int p0 = blockIdx.x * 256;
    const int i0 = blockIdx.y * isplit;
    float acc[15];
    #pragma unroll
    for (int j = 0; j < 15; ++j) acc[j] = 0.f;

    for (int ch = 0; ch < isplit; ch += 32) {
        __syncthreads();
        #pragma unroll
        for (int g = 0; g < 8; ++g) {
            int r = g * 32 + (t >> 3);
            int i4 = (t & 7) * 4;
            float4 v = *(const float4*)(A + (size_t)(p0 + r) * 4096 + i0 + ch + i4);
            lds[r][i4 + 0] = v.x; lds[r][i4 + 1] = v.y;
            lds[r][i4 + 2] = v.z; lds[r][i4 + 3] = v.w;
        }
        __syncthreads();
        const float* bw = B16 + (size_t)(i0 + ch) * 16;   // wave-uniform
        #pragma unroll
        for (int ii = 0; ii < 32; ++ii) {
            float av = lds[t][ii];
            #pragma unroll
            for (int j = 0; j < 15; ++j)
                acc[j] = fmaf(av, bw[ii * 16 + j], acc[j]);
        }
    }
    float* op = partial + ((size_t)blockIdx.y * gridDim.x * 256 + p0 + t) * 16;
    float4 o0 = {acc[0], acc[1], acc[2], acc[3]};
    float4 o1 = {acc[4], acc[5], acc[6], acc[7]};
    float4 o2 = {acc[8], acc[9], acc[10], acc[11]};
    float4 o3 = {acc[12], acc[13], acc[14], 0.f};
    ((float4*)op)[0] = o0; ((float4*)op)[1] = o1;
    ((float4*)op)[2] = o2; ((float4*)op)[3] = o3;
}

// ---------- 4. reduce partial1 -> Wf16 [4096][16]; block 256 computes bfv ----------
__global__ __launch_bounds__(256) void reduce_wf(
        const float* __restrict__ partial1, const float* __restrict__ b2,
        const float* __restrict__ Wcat16, const float* __restrict__ bc,
        const float* __restrict__ br, float* __restrict__ Wf16,
        float* __restrict__ bfv) {
    const int t = threadIdx.x;
    if (blockIdx.x < 256) {
        int idx = blockIdx.x * 256 + t;          // over 65536
        float s = 0.f;
        #pragma unroll
        for (int sp = 0; sp < 16; ++sp) s += partial1[sp * 65536 + idx];
        Wf16[idx] = s;
    } else {
        float acc[15];
        #pragma unroll
        for (int j = 0; j < 15; ++j) acc[j] = 0.f;
        for (int i = t; i < 4096; i += 256) {
            float bv = b2[i];
            #pragma unroll
            for (int j = 0; j < 15; ++j) acc[j] += bv * Wcat16[i * 16 + j];
        }
        const int lane = t & 63, wv = t >> 6;
        __shared__ float red[4][15];
        #pragma unroll
        for (int j = 0; j < 15; ++j) {
            float x = acc[j];
            #pragma unroll
            for (int off = 32; off >= 1; off >>= 1) x += __shfl_xor(x, off, 64);
            if (lane == 0) red[wv][j] = x;
        }
        __syncthreads();
        if (t < 15)
            bfv[t] = red[0][t] + red[1][t] + red[2][t] + red[3][t]
                   + ((t < 3) ? bc[t] : br[t - 3]);
    }
}

// ---------- 5. reduce partial2 (r-order) -> WbigT bf16 [16][k'] (permuted write);
//             block 98 computes bbig ----------
__global__ __launch_bounds__(256) void reduce_wbig(
        const float* __restrict__ partial2, const float* __restrict__ Wf16,
        const float* __restrict__ bfv, const float* __restrict__ b1,
        unsigned short* __restrict__ WbigT, float* __restrict__ bbig) {
    const int t = threadIdx.x;
    if (blockIdx.x < 98) {
        const int r = blockIdx.x * 256 + t;      // W1 row index (linear)
        float sj[16];
        #pragma unroll
        for (int j = 0; j < 16; ++j) sj[j] = 0.f;
        #pragma unroll
        for (int sp = 0; sp < 8; ++sp) {
            const float4* pp = (const float4*)(partial2 + ((size_t)sp * 25088 + r) * 16);
            float4 a = pp[0], b = pp[1], c = pp[2], d = pp[3];
            sj[0] += a.x; sj[1] += a.y; sj[2]  += a.z; sj[3]  += a.w;
            sj[4] += b.x; sj[5] += b.y; sj[6]  += b.z; sj[7]  += b.w;
            sj[8] += c.x; sj[9] += c.y; sj[10] += c.z; sj[11] += c.w;
            sj[12] += d.x; sj[13] += d.y; sj[14] += d.z; sj[15] += d.w;
        }
        const int c = r / 49, bin = r - c * 49;
        const int p = bin * 512 + c;             // k' index
        #pragma unroll
        for (int j = 0; j < 16; ++j)
            WbigT[(size_t)j * 25088 + p] = f2bf(sj[j]);
    } else {
        float acc[15];
        #pragma unroll
        for (int j = 0; j < 15; ++j) acc[j] = 0.f;
        for (int i = t; i < 4096; i += 256) {
            float bv = b1[i];
            #pragma unroll
            for (int j = 0; j < 15; ++j) acc[j] += bv * Wf16[i * 16 + j];
        }
        const int lane = t & 63, wv = t >> 6;
        __shared__ float red[4][15];
        #pragma unroll
        for (int j = 0; j < 15; ++j) {
            float x = acc[j];
            #pragma unroll
            for (int off = 32; off >= 1; off >>= 1) x += __shfl_xor(x, off, 64);
            if (lane == 0) red[wv][j] = x;
        }
        __syncthreads();
        if (t < 16) {
            float s = 0.f;
            if (t < 15)
                s = red[0][t] + red[1][t] + red[2][t] + red[3][t] + bfv[t];
            bbig[t] = s;
        }
    }
}

// ---------- 6. final GEMM: pooled[1024][25088] @ WbigT^T -> partialG[8][1024][16] ----
__global__ __launch_bounds__(256) void final_gemm(
        const unsigned short* __restrict__ pooled,
        const unsigned short* __restrict__ WbigT,
        float* __restrict__ partialG) {
    const int t = threadIdx.x, lane = t & 63, wave = t >> 6;
    const int m0 = blockIdx.x * 16, kz = blockIdx.y;
    const int lr = lane & 15, lks = lane >> 4;
    f32x4 acc = {0.f, 0.f, 0.f, 0.f};
    const unsigned short* arow = pooled + (size_t)(m0 + lr) * 25088 + kz * 3136 + lks * 8;
    const unsigned short* brow = WbigT + (size_t)lr * 25088 + kz * 3136 + lks * 8;
    for (int s = wave; s < 98; s += 4) {
        s16x8 a = *(const s16x8*)(arow + s * 32);
        s16x8 b = *(const s16x8*)(brow + s * 32);
        acc = __builtin_amdgcn_mfma_f32_16x16x32_bf16(a, b, acc, 0, 0, 0);
    }
    __shared__ float red[4][64][4];
    #pragma unroll
    for (int r = 0; r < 4; ++r) red[wave][lane][r] = acc[r];
    __syncthreads();
    if (wave == 0) {
        #pragma unroll
        for (int r = 0; r < 4; ++r) {
            float s = red[0][lane][r] + red[1][lane][r] + red[2][lane][r] + red[3][lane][r];
            int row = m0 + (lane >> 4) * 4 + r;
            partialG[((size_t)kz * 1024 + row) * 16 + (lane & 15)] = s;
        }
    }
}

// ---------- 7. finalize: sum 8 partials + bbig, softmax(3), write out ----------
__global__ __launch_bounds__(256) void finalize_kernel(
        const float* __restrict__ partialG, const float* __restrict__ bbig,
        float* __restrict__ out) {
    const int m = blockIdx.x * 256 + threadIdx.x;   // 0..1023
    float v[15];
    #pragma unroll
    for (int j = 0; j < 15; ++j) v[j] = bbig[j];
    for (int kz = 0; kz < 8; ++kz) {
        const float* p = partialG + ((size_t)kz * 1024 + m) * 16;
        #pragma unroll
        for (int j = 0; j < 15; ++j) v[j] += p[j];
    }
    float mx = fmaxf(v[0], fmaxf(v[1], v[2]));
    float e0 = expf(v[0] - mx), e1 = expf(v[1] - mx), e2 = expf(v[2] - mx);
    float inv = 1.f / (e0 + e1 + e2);
    out[m * 3 + 0] = e0 * inv;
    out[m * 3 + 1] = e1 * inv;
    out[m * 3 + 2] = e2 * inv;
    #pragma unroll
    for (int j = 3; j < 15; ++j) out[3072 + m * 12 + (j - 3)] = v[j];
}

// ---------- launch ----------
extern "C" void kernel_launch(void* const* d_in, const int* in_sizes, int n_in,
                              void* d_out, int out_size, void* d_ws, size_t ws_size,
                              hipStream_t stream) {
    const float* featmap = (const float*)d_in[0];
    const int*   roi     = (const int*)d_in[1];
    const float* W1      = (const float*)d_in[2];
    const float* b1      = (const float*)d_in[3];
    const float* W2      = (const float*)d_in[4];
    const float* b2      = (const float*)d_in[5];
    const float* Wc      = (const float*)d_in[6];
    const float* bc      = (const float*)d_in[7];
    const float* Wr      = (const float*)d_in[8];
    const float* br      = (const float*)d_in[9];
    float* out = (float*)d_out;

    // workspace layout (bytes, 16-aligned)
    char* ws = (char*)d_ws;
    unsigned short* pooled   = (unsigned short*)(ws);                // 51,380,224  [1024][25088] bf16 (k')
    unsigned short* fmT      = (unsigned short*)(ws + 51380224);     //  4,300,800  [4200][512] bf16
    float*          Wcat16   = (float*)        (ws + 55681024);      //    262,144  [4096][16] f32
    float*          Wf16     = (float*)        (ws + 55943168);      //    262,144  [4096][16] f32
    float*          bfv      = (float*)        (ws + 56205312);      //         64
    float*          bbig     = (float*)        (ws + 56205376);      //         64  [16]
    float*          partial1 = (float*)        (ws + 56205440);      //  4,194,304  [16][4096][16] f32
    float*          partial2 = (float*)        (ws + 60399744);      // 12,845,056  [8][25088][16] f32 (r-order)
    unsigned short* WbigT    = (unsigned short*)(ws + 73244800);     //    802,816  [16][25088] bf16 (k'-order)
    float*          partialG = (float*)        (ws + 74047616);      //    524,288  [8][1024][16] f32

    transpose_fm<<<dim3(132, 16), dim3(32, 8), 0, stream>>>(featmap, fmT);
    pool3<<<1024, 256, 0, stream>>>(fmT, roi, pooled);
    prep_wcat<<<256, 256, 0, stream>>>(Wc, Wr, Wcat16);
    skinny_gemm<<<dim3(16, 16), 256, 0, stream>>>(W2, Wcat16, partial1, 256);
    reduce_wf<<<257, 256, 0, stream>>>(partial1, b2, Wcat16, bc, br, Wf16, bfv);
    skinny_gemm<<<dim3(98, 8), 256, 0, stream>>>(W1, Wf16, partial2, 512);
    reduce_wbig<<<99, 256, 0, stream>>>(partial2, Wf16, bfv, b1, WbigT, bbig);
    final_gemm<<<dim3(64, 8), 256, 0, stream>>>(pooled, WbigT, partialG);
    finalize_kernel<<<4, 256, 0, stream>>>(partialG, bbig, out);
}

// Round 8
// 228.137 us; speedup vs baseline: 4.6153x; 1.2600x over previous
//
#include <hip/hip_runtime.h>
#include <hip/hip_bf16.h>
#include <cstdint>
#include <cstddef>

// ---------- types ----------
typedef __attribute__((ext_vector_type(4))) float f32x4;
typedef __attribute__((ext_vector_type(8))) short s16x8;

__device__ __forceinline__ unsigned short f2bf(float f) {
    union { float f; unsigned u; } v; v.f = f;
    unsigned u = v.u;
    u += 0x7fffu + ((u >> 16) & 1u);      // round-to-nearest-even
    return (unsigned short)(u >> 16);
}
__device__ __forceinline__ float bf2f(unsigned short u) {
    union { unsigned u; float f; } v; v.u = ((unsigned)u) << 16; return v.f;
}
__device__ __forceinline__ float lo_f(unsigned v) {   // low bf16 -> f32 (exact)
    union { unsigned u; float f; } w; w.u = v << 16; return w.f;
}
__device__ __forceinline__ float hi_f(unsigned v) {   // high bf16 -> f32 (exact)
    union { unsigned u; float f; } w; w.u = v & 0xffff0000u; return w.f;
}

// =====================================================================
// Network is LINEAR: out_pre = pooled @ Wbig + bbig,
//   Wbig = W1 @ W2 @ [Wc|Wr],  bbig = ((b1@W2)+b2)@[Wc|Wr] + [bc|br].
// Skinny GEMMs (N=15) use LDS-free per-wave MFMA: A-frag read directly
// from global f32 (one 128B line per row per k-step) + in-reg bf16 cvt;
// B is a tiny bf16 [16][4096] transposed matrix resident in L2.
// pooled k' ordering: pooled[n][bin*512+c] <-> W1 row (c*49+bin); the
// permutation is applied at the tiny WbigT write (reduce_wbig).
// =====================================================================

// ---------- 0. featmap transpose: fm[512][4200] f32 -> fmT[4200][512] bf16 ----------
__global__ __launch_bounds__(256) void transpose_fm(
        const float* __restrict__ fm, unsigned short* __restrict__ fmT) {
    __shared__ float tile[32][33];
    int p0 = blockIdx.x * 32, c0 = blockIdx.y * 32;
    int tx = threadIdx.x, ty = threadIdx.y;      // (32,8)
    #pragma unroll
    for (int yy = ty; yy < 32; yy += 8) {
        int p = p0 + tx;
        if (p < 4200) tile[yy][tx] = fm[(size_t)(c0 + yy) * 4200 + p];
    }
    __syncthreads();
    #pragma unroll
    for (int yy = ty; yy < 32; yy += 8) {
        int p = p0 + yy;
        if (p < 4200) fmT[(size_t)p * 512 + c0 + tx] = f2bf(tile[tx][yy]);
    }
}

// ---------- 1. ROI max pooling: exact-window batched loads, 4 ch/thread ----------
// Window spans are block-uniform and in [1,5]; a 25-case switch issues exactly
// hspan*wspan independent loads (one drain), no divergence, no clamp waste.
#define PB(NH, NW) { \
    uint2 v[NH * NW]; \
    _Pragma("unroll") for (int r = 0; r < NH; ++r) \
        _Pragma("unroll") for (int s = 0; s < NW; ++s) \
            v[r * NW + s] = *(const uint2*)(base + ho[r] + wo[s]); \
    float a0 = lo_f(v[0].x), a1 = hi_f(v[0].x); \
    float a2 = lo_f(v[0].y), a3 = hi_f(v[0].y); \
    _Pragma("unroll") for (int q = 1; q < NH * NW; ++q) { \
        a0 = fmaxf(a0, lo_f(v[q].x)); a1 = fmaxf(a1, hi_f(v[q].x)); \
        a2 = fmaxf(a2, lo_f(v[q].y)); a3 = fmaxf(a3, hi_f(v[q].y)); } \
    m0 = a0; m1 = a1; m2 = a2; m3 = a3; } break;

__global__ __launch_bounds__(256) void pool4(
        const unsigned short* __restrict__ fmT, const int* __restrict__ roi,
        unsigned short* __restrict__ pooled) {
    const int n = blockIdx.x;
    __shared__ int hoff[7][5], woff[7][5], hcnt[7], wcnt[7];
    if (threadIdx.x == 0) {
        int x0 = roi[n*4+0] / 16, y0 = roi[n*4+1] / 16;
        int x1 = roi[n*4+2] / 16, y1 = roi[n*4+3] / 16;
        if (x1 - x0 <= 1) { if (x1 < 84) x1 += 1; else x0 -= 1; }
        if (y1 - y0 <= 1) { if (y1 < 50) y1 += 1; else y0 -= 1; }
        int xs = min(max(x0, 0), 84), xe = min(max(x1, 0), 84);
        int ys = min(max(y0, 0), 50), ye = min(max(y1, 0), 50);
        int Lx = xe - xs, Ly = ye - ys;
        #pragma unroll
        for (int i = 0; i < 7; ++i) {
            int b0 = ys + (i * Ly) / 7, b1 = ys + ((i + 1) * Ly + 6) / 7;
            int he = min(b1, b0 + 5);
            hcnt[i] = he - b0;
            int c0 = xs + (i * Lx) / 7, c1 = xs + ((i + 1) * Lx + 6) / 7;
            int we = min(c1, c0 + 5);
            wcnt[i] = we - c0;
            #pragma unroll
            for (int q = 0; q < 5; ++q) {
                hoff[i][q] = (b0 + q) * 43008;   // only q < hcnt accessed
                woff[i][q] = (c0 + q) * 512;
            }
        }
    }
    __syncthreads();
    const int t = threadIdx.x;
    const int g = t >> 7;                 // bin-pair half (wave-uniform)
    const int c4 = (t & 127) * 4;         // 4 channels per thread
    const unsigned short* base = fmT + c4;
    unsigned short* orow = pooled + (size_t)n * 25088;
    for (int bp = 0; bp < 25; ++bp) {
        int bin = bp * 2 + g;
        if (bin < 49) {
            int bi = bin / 7, bj = bin - bi * 7;
            int ho[5], wo[5];
            #pragma unroll
            for (int q = 0; q < 5; ++q) { ho[q] = hoff[bi][q]; wo[q] = woff[bj][q]; }
            int nh = hcnt[bi], nw = wcnt[bj];
            float m0, m1, m2, m3;
            switch ((nh - 1) * 5 + (nw - 1)) {
                case  0: PB(1,1)  case  1: PB(1,2)  case  2: PB(1,3)
                case  3: PB(1,4)  case  4: PB(1,5)
                case  5: PB(2,1)  case  6: PB(2,2)  case  7: PB(2,3)
                case  8: PB(2,4)  case  9: PB(2,5)
                case 10: PB(3,1)  case 11: PB(3,2)  case 12: PB(3,3)
                case 13: PB(3,4)  case 14: PB(3,5)
                case 15: PB(4,1)  case 16: PB(4,2)  case 17: PB(4,3)
                case 18: PB(4,4)  case 19: PB(4,5)
                case 20: PB(5,1)  case 21: PB(5,2)  case 22: PB(5,3)
                case 23: PB(5,4)  case 24: PB(5,5)
                default: m0 = m1 = m2 = m3 = 0.f; break;
            }
            ushort4 o;
            o.x = f2bf(m0); o.y = f2bf(m1); o.z = f2bf(m2); o.w = f2bf(m3);
            *(ushort4*)(orow + bin * 512 + c4) = o;
        }
    }
}

// ---------- 2. WcatT bf16 [16][4096] = [Wc | Wr | 0]^T ----------
__global__ __launch_bounds__(256) void prep_wcat(
        const float* __restrict__ Wc, const float* __restrict__ Wr,
        unsigned short* __restrict__ WcatT) {
    int idx = blockIdx.x * 256 + threadIdx.x;    // 0..65535
    int i = idx >> 4, j = idx & 15;
    float v = (j < 3) ? Wc[i * 3 + j] : (j < 15) ? Wr[i * 12 + (j - 3)] : 0.f;
    WcatT[(size_t)j * 4096 + i] = f2bf(v);
}

// ---------- 3. skinny MFMA GEMM: partial[ky][r][16] = A[r][kchunk] @ BT^T ----------
// LDS-free, barrier-free. 512 thr = 8 waves; wave = 16 rows x 16 cols.
// A-frag: rows r0+lr, k = k0+s*32+lks*8 (+0..7): two float4 f32 loads ->
// in-reg bf16 cvt (lanes of a wave cover one full 128B line per row).
// B-frag: BT[lr][same k] bf16 direct (L2-resident, 128 KB).
__global__ __launch_bounds__(512) void skinny_mfma(
        const float* __restrict__ A, const unsigned short* __restrict__ BT,
        float* __restrict__ partial, int R, int kchunk) {
    const int t = threadIdx.x, lane = t & 63, wave = t >> 6;
    const int r0 = blockIdx.x * 128 + wave * 16;
    const int k0 = blockIdx.y * kchunk;
    const int lr = lane & 15, lks = lane >> 4;
    const int steps = kchunk >> 5;
    const float* ap = A + (size_t)(r0 + lr) * 4096 + k0 + lks * 8;
    const unsigned short* bp = BT + (size_t)lr * 4096 + k0 + lks * 8;
    f32x4 acc = {0.f, 0.f, 0.f, 0.f};
    for (int s = 0; s < steps; ++s) {
        float4 f0 = *(const float4*)(ap + s * 32);
        float4 f1 = *(const float4*)(ap + s * 32 + 4);
        s16x8 b = *(const s16x8*)(bp + s * 32);
        union { unsigned short us[8]; s16x8 v; } a;
        a.us[0] = f2bf(f0.x); a.us[1] = f2bf(f0.y);
        a.us[2] = f2bf(f0.z); a.us[3] = f2bf(f0.w);
        a.us[4] = f2bf(f1.x); a.us[5] = f2bf(f1.y);
        a.us[6] = f2bf(f1.z); a.us[7] = f2bf(f1.w);
        acc = __builtin_amdgcn_mfma_f32_16x16x32_bf16(a.v, b, acc, 0, 0, 0);
    }
    const int row = r0 + (lane >> 4) * 4;        // + q
    float* op = partial + ((size_t)blockIdx.y * R + row) * 16 + lr;
    #pragma unroll
    for (int q = 0; q < 4; ++q) op[q * 16] = acc[q];
}

// ---------- 4. reduce partial1 -> Wf16 f32 + WfT bf16; block 256: bfv ----------
__global__ __launch_bounds__(256) void reduce_wf(
        const float* __restrict__ partial1, const float* __restrict__ b2,
        const float* __restrict__ Wc, const float* __restrict__ Wr,
        const float* __restrict__ bc, const float* __restrict__ br,
        float* __restrict__ Wf16, unsigned short* __restrict__ WfT,
        float* __restrict__ bfv) {
    const int t = threadIdx.x;
    if (blockIdx.x < 256) {
        int idx = blockIdx.x * 256 + t;          // over 65536
        float s = 0.f;
        #pragma unroll
        for (int sp = 0; sp < 8; ++sp) s += partial1[sp * 65536 + idx];
        Wf16[idx] = s;
        int i = idx >> 4, j = idx & 15;
        WfT[(size_t)j * 4096 + i] = f2bf(s);     // col 15 is zeros (WcatT row 15 = 0)
    } else {
        float acc[15];
        #pragma unroll
        for (int j = 0; j < 15; ++j) acc[j] = 0.f;
        for (int i = t; i < 4096; i += 256) {
            float bv = b2[i];
            #pragma unroll
            for (int j = 0; j < 15; ++j)
                acc[j] += bv * ((j < 3) ? Wc[i * 3 + j] : Wr[i * 12 + (j - 3)]);
        }
        const int lane = t & 63, wv = t >> 6;
        __shared__ float red[4][15];
        #pragma unroll
        for (int j = 0; j < 15; ++j) {
            float x = acc[j];
            #pragma unroll
            for (int off = 32; off >= 1; off >>= 1) x += __shfl_xor(x, off, 64);
            if (lane == 0) red[wv][j] = x;
        }
        __syncthreads();
        if (t < 15)
            bfv[t] = red[0][t] + red[1][t] + red[2][t] + red[3][t]
                   + ((t < 3) ? bc[t] : br[t - 3]);
    }
}

// ---------- 5. reduce partial2 (r-order) -> WbigT bf16 [16][k'] (permuted write);
//             block 98 computes bbig ----------
__global__ __launch_bounds__(256) void reduce_wbig(
        const float* __restrict__ partial2, const float* __restrict__ Wf16,
        const float* __restrict__ bfv, const float* __restrict__ b1,
        unsigned short* __restrict__ WbigT, float* __restrict__ bbig) {
    const int t = threadIdx.x;
    if (blockIdx.x < 98) {
        const int r = blockIdx.x * 256 + t;      // W1 row index (linear)
        float sj[16];
        #pragma unroll
        for (int j = 0; j < 16; ++j) sj[j] = 0.f;
        #pragma unroll
        for (int sp = 0; sp < 2; ++sp) {
            const float4* pp = (const float4*)(partial2 + ((size_t)sp * 25088 + r) * 16);
            float4 a = pp[0], b = pp[1], c = pp[2], d = pp[3];
            sj[0] += a.x; sj[1] += a.y; sj[2]  += a.z; sj[3]  += a.w;
            sj[4] += b.x; sj[5] += b.y; sj[6]  += b.z; sj[7]  += b.w;
            sj[8] += c.x; sj[9] += c.y; sj[10] += c.z; sj[11] += c.w;
            sj[12] += d.x; sj[13] += d.y; sj[14] += d.z; sj[15] += d.w;
        }
        const int c = r / 49, bin = r - c * 49;
        const int p = bin * 512 + c;             // k' index
        #pragma unroll
        for (int j = 0; j < 16; ++j)
            WbigT[(size_t)j * 25088 + p] = f2bf(sj[j]);
    } else {
        float acc[15];
        #pragma unroll
        for (int j = 0; j < 15; ++j) acc[j] = 0.f;
        for (int i = t; i < 4096; i += 256) {
            float bv = b1[i];
            #pragma unroll
            for (int j = 0; j < 15; ++j) acc[j] += bv * Wf16[i * 16 + j];
        }
        const int lane = t & 63, wv = t >> 6;
        __shared__ float red[4][15];
        #pragma unroll
        for (int j = 0; j < 15; ++j) {
            float x = acc[j];
            #pragma unroll
            for (int off = 32; off >= 1; off >>= 1) x += __shfl_xor(x, off, 64);
            if (lane == 0) red[wv][j] = x;
        }
        __syncthreads();
        if (t < 16) {
            float s = 0.f;
            if (t < 15)
                s = red[0][t] + red[1][t] + red[2][t] + red[3][t] + bfv[t];
            bbig[t] = s;
        }
    }
}

// ---------- 6. final GEMM: pooled[1024][25088] @ WbigT^T -> partialG[8][1024][16] ----
__global__ __launch_bounds__(256) void final_gemm(
        const unsigned short* __restrict__ pooled,
        const unsigned short* __restrict__ WbigT,
        float* __restrict__ partialG) {
    const int t = threadIdx.x, lane = t & 63, wave = t >> 6;
    const int m0 = blockIdx.x * 16, kz = blockIdx.y;
    const int lr = lane & 15, lks = lane >> 4;
    f32x4 acc = {0.f, 0.f, 0.f, 0.f};
    const unsigned short* arow = pooled + (size_t)(m0 + lr) * 25088 + kz * 3136 + lks * 8;
    const unsigned short* brow = WbigT + (size_t)lr * 25088 + kz * 3136 + lks * 8;
    for (int s = wave; s < 98; s += 4) {
        s16x8 a = *(const s16x8*)(arow + s * 32);
        s16x8 b = *(const s16x8*)(brow + s * 32);
        acc = __builtin_amdgcn_mfma_f32_16x16x32_bf16(a, b, acc, 0, 0, 0);
    }
    __shared__ float red[4][64][4];
    #pragma unroll
    for (int r = 0; r < 4; ++r) red[wave][lane][r] = acc[r];
    __syncthreads();
    if (wave == 0) {
        #pragma unroll
        for (int r = 0; r < 4; ++r) {
            float s = red[0][lane][r] + red[1][lane][r] + red[2][lane][r] + red[3][lane][r];
            int row = m0 + (lane >> 4) * 4 + r;
            partialG[((size_t)kz * 1024 + row) * 16 + (lane & 15)] = s;
        }
    }
}

// ---------- 7. finalize: sum 8 partials + bbig, softmax(3), write out ----------
__global__ __launch_bounds__(256) void finalize_kernel(
        const float* __restrict__ partialG, const float* __restrict__ bbig,
        float* __restrict__ out) {
    const int m = blockIdx.x * 256 + threadIdx.x;   // 0..1023
    float v[15];
    #pragma unroll
    for (int j = 0; j < 15; ++j) v[j] = bbig[j];
    for (int kz = 0; kz < 8; ++kz) {
        const float* p = partialG + ((size_t)kz * 1024 + m) * 16;
        #pragma unroll
        for (int j = 0; j < 15; ++j) v[j] += p[j];
    }
    float mx = fmaxf(v[0], fmaxf(v[1], v[2]));
    float e0 = expf(v[0] - mx), e1 = expf(v[1] - mx), e2 = expf(v[2] - mx);
    float inv = 1.f / (e0 + e1 + e2);
    out[m * 3 + 0] = e0 * inv;
    out[m * 3 + 1] = e1 * inv;
    out[m * 3 + 2] = e2 * inv;
    #pragma unroll
    for (int j = 3; j < 15; ++j) out[3072 + m * 12 + (j - 3)] = v[j];
}

// ---------- launch ----------
extern "C" void kernel_launch(void* const* d_in, const int* in_sizes, int n_in,
                              void* d_out, int out_size, void* d_ws, size_t ws_size,
                              hipStream_t stream) {
    const float* featmap = (const float*)d_in[0];
    const int*   roi     = (const int*)d_in[1];
    const float* W1      = (const float*)d_in[2];
    const float* b1      = (const float*)d_in[3];
    const float* W2      = (const float*)d_in[4];
    const float* b2      = (const float*)d_in[5];
    const float* Wc      = (const float*)d_in[6];
    const float* bc      = (const float*)d_in[7];
    const float* Wr      = (const float*)d_in[8];
    const float* br      = (const float*)d_in[9];
    float* out = (float*)d_out;

    // workspace layout (bytes, 16-aligned)
    char* ws = (char*)d_ws;
    unsigned short* pooled   = (unsigned short*)(ws);                // 51,380,224  [1024][25088] bf16 (k')
    unsigned short* fmT      = (unsigned short*)(ws + 51380224);     //  4,300,800  [4200][512] bf16
    unsigned short* WcatT    = (unsigned short*)(ws + 55681024);     //    131,072  [16][4096] bf16
    unsigned short* WfT      = (unsigned short*)(ws + 55812096);     //    131,072  [16][4096] bf16
    float*          Wf16     = (float*)        (ws + 55943168);      //    262,144  [4096][16] f32
    float*          bfv      = (float*)        (ws + 56205312);      //         64
    float*          bbig     = (float*)        (ws + 56205376);      //         64  [16]
    float*          partial1 = (float*)        (ws + 56205440);      //  4,194,304  [8][4096][16] f32
    float*          partial2 = (float*)        (ws + 60399744);      //  3,211,264  [2][25088][16] f32 (r-order)
    unsigned short* WbigT    = (unsigned short*)(ws + 63611008);     //    802,816  [16][25088] bf16 (k'-order)
    float*          partialG = (float*)        (ws + 64413824);      //    524,288  [8][1024][16] f32

    transpose_fm<<<dim3(132, 16), dim3(32, 8), 0, stream>>>(featmap, fmT);
    pool4<<<1024, 256, 0, stream>>>(fmT, roi, pooled);
    prep_wcat<<<256, 256, 0, stream>>>(Wc, Wr, WcatT);
    skinny_mfma<<<dim3(32, 8), 512, 0, stream>>>(W2, WcatT, partial1, 4096, 512);
    reduce_wf<<<257, 256, 0, stream>>>(partial1, b2, Wc, Wr, bc, br, Wf16, WfT, bfv);
    skinny_mfma<<<dim3(196, 2), 512, 0, stream>>>(W1, WfT, partial2, 25088, 2048);
    reduce_wbig<<<99, 256, 0, stream>>>(partial2, Wf16, bfv, b1, WbigT, bbig);
    final_gemm<<<dim3(64, 8), 256, 0, stream>>>(pooled, WbigT, partialG);
    finalize_kernel<<<4, 256, 0, stream>>>(partialG, bbig, out);
}

// Round 9
// 214.124 us; speedup vs baseline: 4.9174x; 1.0654x over previous
//
#include <hip/hip_runtime.h>
#include <hip/hip_bf16.h>
#include <cstdint>
#include <cstddef>

// ---------- types ----------
typedef __attribute__((ext_vector_type(4))) float f32x4;
typedef __attribute__((ext_vector_type(8))) short s16x8;

__device__ __forceinline__ unsigned short f2bf(float f) {
    union { float f; unsigned u; } v; v.f = f;
    unsigned u = v.u;
    u += 0x7fffu + ((u >> 16) & 1u);      // round-to-nearest-even
    return (unsigned short)(u >> 16);
}
__device__ __forceinline__ float lo_f(unsigned v) {   // low bf16 -> f32 (exact)
    union { unsigned u; float f; } w; w.u = v << 16; return w.f;
}
__device__ __forceinline__ float hi_f(unsigned v) {   // high bf16 -> f32 (exact)
    union { unsigned u; float f; } w; w.u = v & 0xffff0000u; return w.f;
}

// =====================================================================
// Network is LINEAR: out_pre = pooled @ Wbig + bbig,
//   Wbig = W1 @ W2 @ [Wc|Wr],  bbig = ((b1@W2)+b2)@[Wc|Wr] + [bc|br].
// Round-9: pool (L2-bound) and the W1 skinny GEMM (HBM-bound) are fused
// into ONE dispatch with 3:4 blockIdx interleave so their resource use
// overlaps; transpose_fm+prep_wcat likewise fused.
// pooled k' ordering: pooled[n][bin*512+c] <-> W1 row (c*49+bin).
// =====================================================================

// ---------- A. prep_all: featmap transpose (blocks 0..2111) + WcatT (2112..2367) ----
__global__ __launch_bounds__(256) void prep_all(
        const float* __restrict__ fm, unsigned short* __restrict__ fmT,
        const float* __restrict__ Wc, const float* __restrict__ Wr,
        unsigned short* __restrict__ WcatT) {
    const int bid = blockIdx.x, t = threadIdx.x;
    if (bid < 2112) {
        __shared__ float tile[32][33];
        int p0 = (bid % 132) * 32, c0 = (bid / 132) * 32;
        int tx = t & 31, ty = t >> 5;
        #pragma unroll
        for (int yy = ty; yy < 32; yy += 8) {
            int p = p0 + tx;
            if (p < 4200) tile[yy][tx] = fm[(size_t)(c0 + yy) * 4200 + p];
        }
        __syncthreads();
        #pragma unroll
        for (int yy = ty; yy < 32; yy += 8) {
            int p = p0 + yy;
            if (p < 4200) fmT[(size_t)p * 512 + c0 + tx] = f2bf(tile[tx][yy]);
        }
    } else {
        int idx = (bid - 2112) * 256 + t;        // 0..65535
        int i = idx >> 4, j = idx & 15;
        float v = (j < 3) ? Wc[i * 3 + j] : (j < 15) ? Wr[i * 12 + (j - 3)] : 0.f;
        WcatT[(size_t)j * 4096 + i] = f2bf(v);
    }
}

// ---------- skinny MFMA body (LDS-free, barrier-free) ----------
// wave = 16 rows x 16 cols; A from global f32 (full 128B line per row per
// step) cvt to bf16 in-reg; B = tiny bf16 [16][4096] (L2-resident).
__device__ __forceinline__ void skinny_body(
        const float* __restrict__ A, const unsigned short* __restrict__ BT,
        float* __restrict__ partial, int R, int kchunk,
        int bx, int ky, int t) {
    const int lane = t & 63, wave = t >> 6;
    const int r0 = bx * 128 + wave * 16;
    const int k0 = ky * kchunk;
    const int lr = lane & 15, lks = lane >> 4;
    const int steps = kchunk >> 5;
    const float* ap = A + (size_t)(r0 + lr) * 4096 + k0 + lks * 8;
    const unsigned short* bp = BT + (size_t)lr * 4096 + k0 + lks * 8;
    f32x4 acc = {0.f, 0.f, 0.f, 0.f};
    for (int s = 0; s < steps; ++s) {
        float4 f0 = *(const float4*)(ap + s * 32);
        float4 f1 = *(const float4*)(ap + s * 32 + 4);
        s16x8 b = *(const s16x8*)(bp + s * 32);
        union { unsigned short us[8]; s16x8 v; } a;
        a.us[0] = f2bf(f0.x); a.us[1] = f2bf(f0.y);
        a.us[2] = f2bf(f0.z); a.us[3] = f2bf(f0.w);
        a.us[4] = f2bf(f1.x); a.us[5] = f2bf(f1.y);
        a.us[6] = f2bf(f1.z); a.us[7] = f2bf(f1.w);
        acc = __builtin_amdgcn_mfma_f32_16x16x32_bf16(a.v, b, acc, 0, 0, 0);
    }
    const int row = r0 + (lane >> 4) * 4;
    float* op = partial + ((size_t)ky * R + row) * 16 + lr;
    #pragma unroll
    for (int q = 0; q < 4; ++q) op[q * 16] = acc[q];
}

// ---------- B. skinny W2: partial1[8][4096][16] = W2 @ WcatT^T ----------
__global__ __launch_bounds__(512) void skinny_w2(
        const float* __restrict__ W2, const unsigned short* __restrict__ WcatT,
        float* __restrict__ partial1) {
    skinny_body(W2, WcatT, partial1, 4096, 512, blockIdx.x, blockIdx.y, threadIdx.x);
}

// ---------- C. reduce partial1 -> Wf16 f32 + WfT bf16; block 256: bfv ----------
__global__ __launch_bounds__(256) void reduce_wf(
        const float* __restrict__ partial1, const float* __restrict__ b2,
        const float* __restrict__ Wc, const float* __restrict__ Wr,
        const float* __restrict__ bc, const float* __restrict__ br,
        float* __restrict__ Wf16, unsigned short* __restrict__ WfT,
        float* __restrict__ bfv) {
    const int t = threadIdx.x;
    if (blockIdx.x < 256) {
        int idx = blockIdx.x * 256 + t;          // over 65536
        float s = 0.f;
        #pragma unroll
        for (int sp = 0; sp < 8; ++sp) s += partial1[sp * 65536 + idx];
        Wf16[idx] = s;
        int i = idx >> 4, j = idx & 15;
        WfT[(size_t)j * 4096 + i] = f2bf(s);     // row 15 stays zero
    } else {
        float acc[15];
        #pragma unroll
        for (int j = 0; j < 15; ++j) acc[j] = 0.f;
        for (int i = t; i < 4096; i += 256) {
            float bv = b2[i];
            #pragma unroll
            for (int j = 0; j < 15; ++j)
                acc[j] += bv * ((j < 3) ? Wc[i * 3 + j] : Wr[i * 12 + (j - 3)]);
        }
        const int lane = t & 63, wv = t >> 6;
        __shared__ float red[4][15];
        #pragma unroll
        for (int j = 0; j < 15; ++j) {
            float x = acc[j];
            #pragma unroll
            for (int off = 32; off >= 1; off >>= 1) x += __shfl_xor(x, off, 64);
            if (lane == 0) red[wv][j] = x;
        }
        __syncthreads();
        if (t < 15)
            bfv[t] = red[0][t] + red[1][t] + red[2][t] + red[3][t]
                   + ((t < 3) ? bc[t] : br[t - 3]);
    }
}

// ---------- D. megaB: pool (1024 virtual blocks) + skinny W1 (784), 3:4 mix ----------
#define PB(NH, NW) { \
    uint2 v[NH * NW]; \
    _Pragma("unroll") for (int r = 0; r < NH; ++r) \
        _Pragma("unroll") for (int s = 0; s < NW; ++s) \
            v[r * NW + s] = *(const uint2*)(base + ho[r] + wo[s]); \
    float a0 = lo_f(v[0].x), a1 = hi_f(v[0].x); \
    float a2 = lo_f(v[0].y), a3 = hi_f(v[0].y); \
    _Pragma("unroll") for (int q = 1; q < NH * NW; ++q) { \
        a0 = fmaxf(a0, lo_f(v[q].x)); a1 = fmaxf(a1, hi_f(v[q].x)); \
        a2 = fmaxf(a2, lo_f(v[q].y)); a3 = fmaxf(a3, hi_f(v[q].y)); } \
    m0 = a0; m1 = a1; m2 = a2; m3 = a3; } break;

__global__ __launch_bounds__(512) void megaB(
        const unsigned short* __restrict__ fmT, const int* __restrict__ roi,
        unsigned short* __restrict__ pooled,
        const float* __restrict__ W1, const unsigned short* __restrict__ WfT,
        float* __restrict__ partial2) {
    const int g7 = blockIdx.x / 7, r7 = blockIdx.x % 7;
    const int t = threadIdx.x;
    if (r7 < 3) {
        // ---- skinny W1 block ----
        const int sb = g7 * 3 + r7;
        if (sb >= 784) return;
        const int ky = sb / 196, bx = sb % 196;
        skinny_body(W1, WfT, partial2, 25088, 1024, bx, ky, t);
    } else {
        // ---- pool block (one ROI) ----
        const int n = g7 * 4 + (r7 - 3);
        if (n >= 1024) return;
        __shared__ int hoff[7][5], woff[7][5], hcnt[7], wcnt[7];
        if (t == 0) {
            int x0 = roi[n*4+0] / 16, y0 = roi[n*4+1] / 16;
            int x1 = roi[n*4+2] / 16, y1 = roi[n*4+3] / 16;
            if (x1 - x0 <= 1) { if (x1 < 84) x1 += 1; else x0 -= 1; }
            if (y1 - y0 <= 1) { if (y1 < 50) y1 += 1; else y0 -= 1; }
            int xs = min(max(x0, 0), 84), xe = min(max(x1, 0), 84);
            int ys = min(max(y0, 0), 50), ye = min(max(y1, 0), 50);
            int Lx = xe - xs, Ly = ye - ys;
            #pragma unroll
            for (int i = 0; i < 7; ++i) {
                int b0 = ys + (i * Ly) / 7, b1 = ys + ((i + 1) * Ly + 6) / 7;
                hcnt[i] = min(b1, b0 + 5) - b0;
                int c0 = xs + (i * Lx) / 7, c1 = xs + ((i + 1) * Lx + 6) / 7;
                wcnt[i] = min(c1, c0 + 5) - c0;
                #pragma unroll
                for (int q = 0; q < 5; ++q) {
                    hoff[i][q] = (b0 + q) * 43008;
                    woff[i][q] = (c0 + q) * 512;
                }
            }
        }
        __syncthreads();
        const int g = t >> 7;                 // 4 bin groups
        const int c4 = (t & 127) * 4;
        const unsigned short* base = fmT + c4;
        unsigned short* orow = pooled + (size_t)n * 25088;
        for (int bp = 0; bp < 13; ++bp) {
            int bin = bp * 4 + g;
            if (bin < 49) {
                int bi = bin / 7, bj = bin - bi * 7;
                int ho[5], wo[5];
                #pragma unroll
                for (int q = 0; q < 5; ++q) { ho[q] = hoff[bi][q]; wo[q] = woff[bj][q]; }
                int nh = hcnt[bi], nw = wcnt[bj];
                float m0, m1, m2, m3;
                switch ((nh - 1) * 5 + (nw - 1)) {
                    case  0: PB(1,1)  case  1: PB(1,2)  case  2: PB(1,3)
                    case  3: PB(1,4)  case  4: PB(1,5)
                    case  5: PB(2,1)  case  6: PB(2,2)  case  7: PB(2,3)
                    case  8: PB(2,4)  case  9: PB(2,5)
                    case 10: PB(3,1)  case 11: PB(3,2)  case 12: PB(3,3)
                    case 13: PB(3,4)  case 14: PB(3,5)
                    case 15: PB(4,1)  case 16: PB(4,2)  case 17: PB(4,3)
                    case 18: PB(4,4)  case 19: PB(4,5)
                    case 20: PB(5,1)  case 21: PB(5,2)  case 22: PB(5,3)
                    case 23: PB(5,4)  case 24: PB(5,5)
                    default: m0 = m1 = m2 = m3 = 0.f; break;
                }
                ushort4 o;
                o.x = f2bf(m0); o.y = f2bf(m1); o.z = f2bf(m2); o.w = f2bf(m3);
                *(ushort4*)(orow + bin * 512 + c4) = o;
            }
        }
    }
}

// ---------- E. reduce partial2 (r-order, 4 splits) -> WbigT bf16 (k'-permuted);
//             block 98 computes bbig ----------
__global__ __launch_bounds__(256) void reduce_wbig(
        const float* __restrict__ partial2, const float* __restrict__ Wf16,
        const float* __restrict__ bfv, const float* __restrict__ b1,
        unsigned short* __restrict__ WbigT, float* __restrict__ bbig) {
    const int t = threadIdx.x;
    if (blockIdx.x < 98) {
        const int r = blockIdx.x * 256 + t;      // W1 row (linear)
        float sj[16];
        #pragma unroll
        for (int j = 0; j < 16; ++j) sj[j] = 0.f;
        #pragma unroll
        for (int sp = 0; sp < 4; ++sp) {
            const float4* pp = (const float4*)(partial2 + ((size_t)sp * 25088 + r) * 16);
            float4 a = pp[0], b = pp[1], c = pp[2], d = pp[3];
            sj[0] += a.x; sj[1] += a.y; sj[2]  += a.z; sj[3]  += a.w;
            sj[4] += b.x; sj[5] += b.y; sj[6]  += b.z; sj[7]  += b.w;
            sj[8] += c.x; sj[9] += c.y; sj[10] += c.z; sj[11] += c.w;
            sj[12] += d.x; sj[13] += d.y; sj[14] += d.z; sj[15] += d.w;
        }
        const int c = r / 49, bin = r - c * 49;
        const int p = bin * 512 + c;             // k' index
        #pragma unroll
        for (int j = 0; j < 16; ++j)
            WbigT[(size_t)j * 25088 + p] = f2bf(sj[j]);
    } else {
        float acc[15];
        #pragma unroll
        for (int j = 0; j < 15; ++j) acc[j] = 0.f;
        for (int i = t; i < 4096; i += 256) {
            float bv = b1[i];
            #pragma unroll
            for (int j = 0; j < 15; ++j) acc[j] += bv * Wf16[i * 16 + j];
        }
        const int lane = t & 63, wv = t >> 6;
        __shared__ float red[4][15];
        #pragma unroll
        for (int j = 0; j < 15; ++j) {
            float x = acc[j];
            #pragma unroll
            for (int off = 32; off >= 1; off >>= 1) x += __shfl_xor(x, off, 64);
            if (lane == 0) red[wv][j] = x;
        }
        __syncthreads();
        if (t < 16) {
            float s = 0.f;
            if (t < 15)
                s = red[0][t] + red[1][t] + red[2][t] + red[3][t] + bfv[t];
            bbig[t] = s;
        }
    }
}

// ---------- F. final GEMM: pooled @ WbigT^T -> partialG[8][1024][16] ----------
__global__ __launch_bounds__(256) void final_gemm(
        const unsigned short* __restrict__ pooled,
        const unsigned short* __restrict__ WbigT,
        float* __restrict__ partialG) {
    const int t = threadIdx.x, lane = t & 63, wave = t >> 6;
    const int m0 = blockIdx.x * 16, kz = blockIdx.y;
    const int lr = lane & 15, lks = lane >> 4;
    f32x4 acc = {0.f, 0.f, 0.f, 0.f};
    const unsigned short* arow = pooled + (size_t)(m0 + lr) * 25088 + kz * 3136 + lks * 8;
    const unsigned short* brow = WbigT + (size_t)lr * 25088 + kz * 3136 + lks * 8;
    for (int s = wave; s < 98; s += 4) {
        s16x8 a = *(const s16x8*)(arow + s * 32);
        s16x8 b = *(const s16x8*)(brow + s * 32);
        acc = __builtin_amdgcn_mfma_f32_16x16x32_bf16(a, b, acc, 0, 0, 0);
    }
    __shared__ float red[4][64][4];
    #pragma unroll
    for (int r = 0; r < 4; ++r) red[wave][lane][r] = acc[r];
    __syncthreads();
    if (wave == 0) {
        #pragma unroll
        for (int r = 0; r < 4; ++r) {
            float s = red[0][lane][r] + red[1][lane][r] + red[2][lane][r] + red[3][lane][r];
            int row = m0 + (lane >> 4) * 4 + r;
            partialG[((size_t)kz * 1024 + row) * 16 + (lane & 15)] = s;
        }
    }
}

// ---------- G. finalize: sum 8 partials + bbig, softmax(3), write out ----------
__global__ __launch_bounds__(256) void finalize_kernel(
        const float* __restrict__ partialG, const float* __restrict__ bbig,
        float* __restrict__ out) {
    const int m = blockIdx.x * 256 + threadIdx.x;   // 0..1023
    float v[15];
    #pragma unroll
    for (int j = 0; j < 15; ++j) v[j] = bbig[j];
    for (int kz = 0; kz < 8; ++kz) {
        const float* p = partialG + ((size_t)kz * 1024 + m) * 16;
        #pragma unroll
        for (int j = 0; j < 15; ++j) v[j] += p[j];
    }
    float mx = fmaxf(v[0], fmaxf(v[1], v[2]));
    float e0 = expf(v[0] - mx), e1 = expf(v[1] - mx), e2 = expf(v[2] - mx);
    float inv = 1.f / (e0 + e1 + e2);
    out[m * 3 + 0] = e0 * inv;
    out[m * 3 + 1] = e1 * inv;
    out[m * 3 + 2] = e2 * inv;
    #pragma unroll
    for (int j = 3; j < 15; ++j) out[3072 + m * 12 + (j - 3)] = v[j];
}

// ---------- launch ----------
extern "C" void kernel_launch(void* const* d_in, const int* in_sizes, int n_in,
                              void* d_out, int out_size, void* d_ws, size_t ws_size,
                              hipStream_t stream) {
    const float* featmap = (const float*)d_in[0];
    const int*   roi     = (const int*)d_in[1];
    const float* W1      = (const float*)d_in[2];
    const float* b1      = (const float*)d_in[3];
    const float* W2      = (const float*)d_in[4];
    const float* b2      = (const float*)d_in[5];
    const float* Wc      = (const float*)d_in[6];
    const float* bc      = (const float*)d_in[7];
    const float* Wr      = (const float*)d_in[8];
    const float* br      = (const float*)d_in[9];
    float* out = (float*)d_out;

    // workspace layout (bytes, 16-aligned)
    char* ws = (char*)d_ws;
    unsigned short* pooled   = (unsigned short*)(ws);                // 51,380,224  [1024][25088] bf16 (k')
    unsigned short* fmT      = (unsigned short*)(ws + 51380224);     //  4,300,800  [4200][512] bf16
    unsigned short* WcatT    = (unsigned short*)(ws + 55681024);     //    131,072  [16][4096] bf16
    unsigned short* WfT      = (unsigned short*)(ws + 55812096);     //    131,072  [16][4096] bf16
    float*          Wf16     = (float*)        (ws + 55943168);      //    262,144  [4096][16] f32
    float*          bfv      = (float*)        (ws + 56205312);      //         64
    float*          bbig     = (float*)        (ws + 56205376);      //         64  [16]
    float*          partial1 = (float*)        (ws + 56205440);      //  4,194,304  [8][4096][16] f32
    float*          partial2 = (float*)        (ws + 60399744);      //  6,422,528  [4][25088][16] f32 (r-order)
    unsigned short* WbigT    = (unsigned short*)(ws + 66822272);     //    802,816  [16][25088] bf16 (k'-order)
    float*          partialG = (float*)        (ws + 67625088);      //    524,288  [8][1024][16] f32

    prep_all<<<2368, 256, 0, stream>>>(featmap, fmT, Wc, Wr, WcatT);
    skinny_w2<<<dim3(32, 8), 512, 0, stream>>>(W2, WcatT, partial1);
    reduce_wf<<<257, 256, 0, stream>>>(partial1, b2, Wc, Wr, bc, br, Wf16, WfT, bfv);
    megaB<<<1834, 512, 0, stream>>>(fmT, roi, pooled, W1, WfT, partial2);
    reduce_wbig<<<99, 256, 0, stream>>>(partial2, Wf16, bfv, b1, WbigT, bbig);
    final_gemm<<<dim3(64, 8), 256, 0, stream>>>(pooled, WbigT, partialG);
    finalize_kernel<<<4, 256, 0, stream>>>(partialG, bbig, out);
}